// Round 11
// baseline (574.749 us; speedup 1.0000x reference)
//
#include <hip/hip_runtime.h>
#include <math.h>

#define NN 4096

typedef float4 f4;
typedef _Float16 f16;
typedef _Float16 f16x8 __attribute__((ext_vector_type(8)));
typedef _Float16 h4 __attribute__((ext_vector_type(4)));
typedef float f32x4v __attribute__((ext_vector_type(4)));

// adjmm-convention B-frag offset (f16 units): ch = output column, n = reduction (node)
__device__ __forceinline__ size_t frag_off(int CT, int ch, int n) {
  return ((size_t)(n >> 5) * CT + (ch >> 4)) * 512
       + (size_t)((((ch & 15) + (((n & 31) >> 3) << 4)) << 3) + (n & 7));
}
// n-convention B-frag (for wgemm): col = node n (4096 wide -> CT=256), k = feature
__device__ __forceinline__ size_t nfrag_off(int k, int n) {
  return ((size_t)(k >> 5) * 256 + (n >> 4)) * 512
       + (size_t)((((n & 15) + (((k & 31) >> 3) << 4)) << 3) + (k & 7));
}
// A-frag offset (weights, M=128): row o, reduction k
__device__ __forceinline__ size_t afrag_off(int K32, int o, int k) {
  return ((size_t)(o >> 4) * K32 + (k >> 5)) * 512
       + (size_t)((((o & 15) + (((k & 31) >> 3) << 4)) << 3) + (k & 7));
}

// ---------------- adj fp32 -> fp16 A-frags (LDS-staged, coalesced) + colsum partials -------
__global__ __launch_bounds__(256)
void convert_cs2(const float* __restrict__ adj, f16* __restrict__ adj16,
                 float* __restrict__ csp) {
  __shared__ f16 lds16[32][520];
  const int rb = blockIdx.x;        // 128 blocks of 32 rows
  const int cb = blockIdx.y;        // 8 col blocks of 512
  const int t = threadIdx.x;
  const int half = t >> 7;          // 2 row halves of 16
  const int u = t & 127;
  const int c0 = cb * 512 + u * 4;
  float cs0 = 0.f, cs1 = 0.f, cs2 = 0.f, cs3 = 0.f;
  #pragma unroll 4
  for (int r = 0; r < 16; ++r) {
    const int i = rb * 32 + half * 16 + r;
    f4 v = *(const f4*)(adj + (size_t)i * NN + c0);
    cs0 += v.x; cs1 += v.y; cs2 += v.z; cs3 += v.w;
    h4 hv; hv[0] = (f16)v.x; hv[1] = (f16)v.y; hv[2] = (f16)v.z; hv[3] = (f16)v.w;
    *(h4*)&lds16[half * 16 + r][u * 4] = hv;
  }
  f4 cv; cv.x = cs0; cv.y = cs1; cv.z = cs2; cv.w = cs3;
  *(f4*)(csp + (size_t)(rb * 2 + half) * NN + c0) = cv;
  __syncthreads();
  const int rt = rb * 2 + half;
  f16* dst = adj16 + ((size_t)rt * 128 + cb * 16) * 512;
  #pragma unroll
  for (int s = 0; s < 8; ++s) {
    const int e = s * 1024 + u * 8;
    const int bl = e >> 9;
    const int l = (e >> 3) & 63;
    const int row = half * 16 + (l & 15);
    const int col = bl * 32 + (l >> 4) * 8;
    f16x8 fr = *(const f16x8*)&lds16[row][col];
    *(f16x8*)(dst + e) = fr;
  }
}

__global__ void colsum_fin(const float* __restrict__ csp, float* __restrict__ deg_inv) {
  int j = blockIdx.x * 256 + threadIdx.x;
  float s = 0.f;
  for (int rb = 0; rb < 256; ++rb) s += csp[(size_t)rb * NN + j];
  deg_inv[j] = 1.0f / (s + 1e-6f);
}

// ---------------- weight fold 1: per (branch, tap) GEMM into wpart ----------------
__global__ __launch_bounds__(256)
void wfold1(const float* __restrict__ proj_w,
            const float* __restrict__ w0, const float* __restrict__ w1,
            const float* __restrict__ w2, const float* __restrict__ w3,
            float* __restrict__ wpart) {
  __shared__ float projs[128][65];
  __shared__ float wk[64][65];
  const int b = blockIdx.x;
  int br, kp;
  if (b == 0) { br = 0; kp = 0; }
  else if (b < 4) { br = 1; kp = b - 1; }
  else if (b < 9) { br = 2; kp = b - 4; }
  else { br = 3; kp = b - 9; }
  const int Kbr = 2 * br + 1;
  const float* Wbr = (br == 0) ? w0 : (br == 1) ? w1 : (br == 2) ? w2 : w3;
  const int baseo[4] = {0, 8192, 32768, 73728};
  const int t = threadIdx.x;
  #pragma unroll
  for (int r = 0; r < 32; ++r) {
    int e = r * 256 + t; int o = e >> 6, cp = e & 63;
    projs[o][cp] = proj_w[(size_t)o * 256 + br * 64 + cp];
  }
  #pragma unroll
  for (int r = 0; r < 16; ++r) {
    int e = r * 256 + t; int cp = e >> 6, c = e & 63;
    wk[cp][c] = Wbr[(size_t)(cp * 64 + c) * Kbr + kp];
  }
  __syncthreads();
  for (int i = 0; i < 32; ++i) {
    int e = i * 256 + t; int o = e >> 6, c = e & 63;
    float s = 0.f;
    #pragma unroll 8
    for (int cp = 0; cp < 64; ++cp) s += projs[o][cp] * wk[cp][c];
    wpart[baseo[br] + (size_t)(o * 64 + c) * Kbr + kp] = s;
  }
}

// ---------------- weight fold assemble: Weff[o][c][7] + beff ----------------
__global__ void wfold_asm(const float* __restrict__ wpart, const float* __restrict__ proj_w,
                          const float* __restrict__ proj_b,
                          const float* __restrict__ b0, const float* __restrict__ b1,
                          const float* __restrict__ b2, const float* __restrict__ b3,
                          float* __restrict__ Weff, float* __restrict__ beff) {
  const int id = blockIdx.x * 256 + threadIdx.x;
  const int o = id >> 6, c = id & 63;
  const int oc = o * 64 + c;
  #pragma unroll
  for (int k = 0; k < 7; ++k) {
    float s = 0.f;
    if (k == 3)            s += wpart[oc];
    if (k >= 2 && k <= 4)  s += wpart[8192  + oc * 3 + (k - 2)];
    if (k >= 1 && k <= 5)  s += wpart[32768 + oc * 5 + (k - 1)];
    s += wpart[73728 + oc * 7 + k];
    Weff[(size_t)oc * 7 + k] = s;
  }
  if (blockIdx.x == 0 && threadIdx.x < 128) {
    const int oo = threadIdx.x;
    float s = proj_b[oo];
    for (int j = 0; j < 64; ++j) {
      s += proj_w[(size_t)oo * 256 + j] * b0[j];
      s += proj_w[(size_t)oo * 256 + 64 + j] * b1[j];
      s += proj_w[(size_t)oo * 256 + 128 + j] * b2[j];
      s += proj_w[(size_t)oo * 256 + 192 + j] * b3[j];
    }
    beff[oo] = s;
  }
}

// ---------------- weight fold 2: Wcy = kur_wy @ Weff -> f16 A-frags; cyb ----------------
__global__ __launch_bounds__(256)
void wfold2(const float* __restrict__ kur_wy, const float* __restrict__ Weff,
            const float* __restrict__ beff, const float* __restrict__ kur_by,
            const float* __restrict__ kur_bc,
            f16* __restrict__ wcyfrag, float* __restrict__ cyb) {
  __shared__ float wyh[128][65];
  __shared__ float weffL[128][33];
  const int ckb = blockIdx.x * 32;
  const int t = threadIdx.x;
  const int o = t & 127, hh = t >> 7;
  #pragma unroll
  for (int r = 0; r < 16; ++r) {
    int e = r * 256 + t; int op = e >> 5, ck = e & 31;
    weffL[op][ck] = Weff[(size_t)op * 448 + ckb + ck];
  }
  float acc[16];
  #pragma unroll
  for (int i = 0; i < 16; ++i) acc[i] = 0.f;
  float bacc = 0.f;
  for (int h = 0; h < 2; ++h) {
    __syncthreads();
    #pragma unroll
    for (int r = 0; r < 32; ++r) {
      int e = r * 256 + t; int oo = e >> 6, o2 = e & 63;
      wyh[oo][o2] = kur_wy[(size_t)oo * 128 + h * 64 + o2];
    }
    __syncthreads();
    for (int oo = 0; oo < 64; ++oo) {
      float w = wyh[o][oo];
      int op = h * 64 + oo;
      #pragma unroll
      for (int i = 0; i < 16; ++i) acc[i] += w * weffL[op][hh * 16 + i];
      if (t < 128) bacc += w * beff[op];
    }
  }
  #pragma unroll
  for (int i = 0; i < 16; ++i) {
    int ck = ckb + hh * 16 + i;
    int c = ck / 7, kt = ck % 7;
    wcyfrag[afrag_off(14, o, kt * 64 + c)] = (f16)acc[i];
  }
  if (blockIdx.x == 0 && t < 128) cyb[t] = bacc + kur_by[t] + kur_bc[t];
}

// ---------------- convert pat_w / kur_wc / ro_w1 to f16 A-frags ----------------
__global__ void wprep(const float* __restrict__ pat_w, const float* __restrict__ kur_wc,
                      const float* __restrict__ ro_w1,
                      f16* __restrict__ patfrag, f16* __restrict__ wcfrag,
                      f16* __restrict__ row1frag) {
  const int id = blockIdx.x * 256 + threadIdx.x;
  if (id < 57344) {
    int o = id / 448, k = id % 448;
    patfrag[afrag_off(14, o, k)] = (f16)pat_w[id];
  } else if (id < 73728) {
    int e = id - 57344; int o = e >> 7, k = e & 127;
    wcfrag[afrag_off(4, o, k)] = (f16)kur_wc[e];
  } else {
    int e = id - 73728; int o = e >> 7, k = e & 127;
    row1frag[afrag_off(4, o, k)] = (f16)ro_w1[e];
  }
}

// ---------------- x[N,64] -> xT[64][N] + gst coef0 row + fragA (x*deg_inv) ----------------
__global__ void transpose_x(const float* __restrict__ x, const float* __restrict__ deg,
                            float* __restrict__ xT, float* __restrict__ gst,
                            f16* __restrict__ fragA) {
  __shared__ float T[64][65];
  const int nb = blockIdx.x * 64;
  const int t = threadIdx.x;
  #pragma unroll
  for (int r = 0; r < 16; ++r) {
    int e = r * 256 + t; int nl = e >> 6, f = e & 63;
    T[nl][f] = x[(size_t)(nb + nl) * 64 + f];
  }
  __syncthreads();
  #pragma unroll
  for (int r = 0; r < 16; ++r) {
    int e = r * 256 + t; int f = e >> 6, nl = e & 63;
    float v = T[nl][f];
    xT[(size_t)f * NN + nb + nl] = v;
    gst[(size_t)f * 7 * NN + nb + nl] = v;
  }
  #pragma unroll
  for (int k = 0; k < 2; ++k) {
    int fi = k * 256 + t;
    int f = fi >> 3, n0l = (fi & 7) << 3;
    f16x8 fr;
    #pragma unroll
    for (int j = 0; j < 8; ++j) fr[j] = (f16)(T[n0l + j][f] * deg[nb + n0l + j]);
    *(f16x8*)(fragA + frag_off(4, f, nb + n0l)) = fr;
  }
}

// ---------------- im2col: x -> n-frags [k = dk*64+c][n], zero-padded ----------------
__global__ void im2col(const float* __restrict__ x, f16* __restrict__ fragN) {
  const int ot = blockIdx.x * 256 + threadIdx.x;
  const int q = ot >> 12;
  const int n = ot & 4095;
  const int dk = q >> 3;
  const int c0 = (q & 7) * 8;
  const int np = n + dk - 3;
  f16x8 fr;
  if (np >= 0 && np < NN) {
    const float* src = x + (size_t)np * 64 + c0;
    f4 v0 = *(const f4*)src, v1 = *(const f4*)(src + 4);
    fr[0]=(f16)v0.x; fr[1]=(f16)v0.y; fr[2]=(f16)v0.z; fr[3]=(f16)v0.w;
    fr[4]=(f16)v1.x; fr[5]=(f16)v1.y; fr[6]=(f16)v1.z; fr[7]=(f16)v1.w;
  } else {
    #pragma unroll
    for (int j = 0; j < 8; ++j) fr[j] = (f16)0.f;
  }
  *(f16x8*)(fragN + nfrag_off(q * 8, n)) = fr;
}

// ---------------- MFMA split-K GEMM vs adjacency, v5: shared-B waves ----------------
// block b: mt = b&63 (64-node group), kz = b>>6. Wave w owns 16-row tile rt = mt*4+w;
// all 4 waves share the SAME K-range -> B-frags loaded once per block (L1 broadcast).
// Output staged in LDS, written float-coalesced into part[kz][rt][F][16].
template<int F, int KZ>
__global__ __launch_bounds__(256)
void adjmm16(const f16* __restrict__ adj16, const f16* __restrict__ rhs,
             float* __restrict__ part) {
  constexpr int CT = F / 16;
  constexpr int KSB = (NN / KZ) / 32;   // K-steps per block (all waves)
  const int t = threadIdx.x;
  const int lane = t & 63, w = t >> 6;
  const int mt = blockIdx.x & 63;
  const int kz = blockIdx.x >> 6;
  const int rt = mt * 4 + w;
  const int kt0 = kz * KSB;
  const size_t aoff = ((size_t)rt * 128 + kt0) * 512 + (size_t)lane * 8;
  const f16* bb = rhs + (size_t)kt0 * CT * 512 + lane * 8;
  f32x4v acc[CT];
  #pragma unroll
  for (int c = 0; c < CT; ++c) acc[c] = (f32x4v){0.f, 0.f, 0.f, 0.f};
  #pragma unroll 2
  for (int i = 0; i < KSB; ++i) {
    f16x8 a = *(const f16x8*)(adj16 + aoff + (size_t)i * 512);
    #pragma unroll
    for (int c = 0; c < CT; ++c) {
      f16x8 bv = *(const f16x8*)(bb + ((size_t)i * CT + c) * 512);
      acc[c] = __builtin_amdgcn_mfma_f32_16x16x32_f16(a, bv, acc[c], 0, 0, 0);
    }
  }
  // stage per-wave tile, then block-cooperative float-coalesced write
  __shared__ float st[4][CT * 256];
  #pragma unroll
  for (int c = 0; c < CT; ++c)
    *(f32x4v*)(st[w] + c * 256 + lane * 4) = acc[c];
  __syncthreads();
  // part layout: [kz][rt 0..255][ch 0..F-1][16 nodes]; block covers rt = mt*4..+3
  float* pb = part + ((size_t)kz * 256 + (size_t)mt * 4) * F * 16;
  constexpr int TOT = 4 * F * 16;       // floats per block
  #pragma unroll
  for (int s = 0; s < TOT; s += 256) {
    const int e = s + t;
    const int rt_l = e / (F * 16);
    const int rem = e % (F * 16);
    const int ch = rem >> 4, nl = rem & 15;
    // inverse of acc staging: c = ch>>4, lane_s = (ch&15) + ((nl>>2)<<4), j = nl&3
    pb[e] = st[rt_l][(ch >> 4) * 256 + (((ch & 15) + ((nl >> 2) << 4)) << 2) + (nl & 3)];
  }
}

// ---------------- reduce split-K + P epilogue + frag/diff/gst/s1 fusion (f4/thread) -------
// part layout: [z][rt][F][16]
__global__ void reduce_P(const float* __restrict__ part, const float* __restrict__ u,
                         const float* __restrict__ D, float* __restrict__ outp,
                         f16* __restrict__ fragNext, int nextCT,
                         f16* __restrict__ fragDiff, int diffChOff,
                         float* __restrict__ gstf, int coefLo, int coefHi,
                         float* __restrict__ s1buf, const float* __restrict__ deg,
                         int F, int KZ) {
  const int id = blockIdx.x * 256 + threadIdx.x;
  const int ch = id >> 10, n0 = (id & 1023) << 2;
  const size_t base = (size_t)ch * NN + n0;
  const size_t poff = (((size_t)(n0 >> 4)) * F + ch) * 16 + (n0 & 15);
  const size_t pstride = (size_t)256 * F * 16;
  float a0 = 0.f, a1 = 0.f, a2 = 0.f, a3 = 0.f;
  for (int z = 0; z < KZ; ++z) {
    f4 p = *(const f4*)(part + (size_t)z * pstride + poff);
    a0 += p.x; a1 += p.y; a2 += p.z; a3 += p.w;
  }
  f4 u0 = *(const f4*)(u + base);
  float o0 = 0.5f * (u0.x + a0), o1 = 0.5f * (u0.y + a1);
  float o2 = 0.5f * (u0.z + a2), o3 = 0.5f * (u0.w + a3);
  f4 ov; ov.x = o0; ov.y = o1; ov.z = o2; ov.w = o3;
  *(f4*)(outp + base) = ov;
  if (fragNext) {
    f4 dg = *(const f4*)(deg + n0);
    h4 fr;
    fr[0] = (f16)(o0 * dg.x); fr[1] = (f16)(o1 * dg.y);
    fr[2] = (f16)(o2 * dg.z); fr[3] = (f16)(o3 * dg.w);
    *(h4*)(fragNext + frag_off(nextCT, ch, n0)) = fr;
  }
  if (D) {
    f4 d0 = *(const f4*)(D + base);
    float e0 = fabsf(d0.x - o0), e1 = fabsf(d0.y - o1);
    float e2 = fabsf(d0.z - o2), e3 = fabsf(d0.w - o3);
    f4 ev; ev.x = e0; ev.y = e1; ev.z = e2; ev.w = e3;
    if (s1buf) *(f4*)(s1buf + base) = ev;
    if (fragDiff) {
      f4 dg = *(const f4*)(deg + n0);
      h4 fr;
      fr[0] = (f16)(e0 * dg.x); fr[1] = (f16)(e1 * dg.y);
      fr[2] = (f16)(e2 * dg.z); fr[3] = (f16)(e3 * dg.w);
      *(h4*)(fragDiff + frag_off(8, diffChOff + ch, n0)) = fr;
    }
    if (gstf) {
      int coef = (ch < 64) ? coefLo : coefHi;
      if (coef >= 0)
        *(f4*)(gstf + (size_t)((ch & 63) * 7 + coef) * NN + n0) = ev;
    }
  }
}

// ---------------- gstf fp32 rows -> n-frags (LDS transpose) ----------------
__global__ void gst2frag(const float* __restrict__ gstf, f16* __restrict__ fragN) {
  __shared__ float T[64][65];
  const int nb = blockIdx.x * 64;
  const int kb = blockIdx.y * 64;
  const int t = threadIdx.x;
  #pragma unroll
  for (int r = 0; r < 16; ++r) {
    int e = r * 256 + t; int row = e >> 6, col = e & 63;
    T[row][col] = gstf[(size_t)(kb + row) * NN + nb + col];
  }
  __syncthreads();
  #pragma unroll
  for (int h = 0; h < 2; ++h) {
    int idx = h * 256 + t;
    int q = idx >> 6, n = idx & 63;
    f16x8 fr;
    #pragma unroll
    for (int j = 0; j < 8; ++j) fr[j] = (f16)T[q * 8 + j][n];
    *(f16x8*)(fragN + nfrag_off(kb + q * 8, nb + n)) = fr;
  }
}

// ---------------- generic MFMA wgemm (EPI 0/1/2/3 as before) ----------------
template<int K32, int EPI>
__global__ __launch_bounds__(256)
void wgemm(const f16* __restrict__ A, const f16* __restrict__ B,
           const float* __restrict__ bias, float* __restrict__ out,
           f16* __restrict__ ofrag) {
  const int t = threadIdx.x;
  const int lane = t & 63, w = t >> 6;
  const int nb = blockIdx.x * 32;
  const size_t a0b = ((size_t)(2 * w) * K32) * 512 + lane * 8;
  const size_t a1b = ((size_t)(2 * w + 1) * K32) * 512 + lane * 8;
  const size_t b0b = (size_t)(nb >> 4) * 512 + lane * 8;
  f32x4v acc[2][2];
  acc[0][0] = (f32x4v){0,0,0,0}; acc[0][1] = (f32x4v){0,0,0,0};
  acc[1][0] = (f32x4v){0,0,0,0}; acc[1][1] = (f32x4v){0,0,0,0};
  #pragma unroll
  for (int i = 0; i < K32; ++i) {
    f16x8 a0 = *(const f16x8*)(A + a0b + (size_t)i * 512);
    f16x8 a1 = *(const f16x8*)(A + a1b + (size_t)i * 512);
    f16x8 b0 = *(const f16x8*)(B + b0b + (size_t)i * 256 * 512);
    f16x8 b1 = *(const f16x8*)(B + b0b + (size_t)i * 256 * 512 + 512);
    acc[0][0] = __builtin_amdgcn_mfma_f32_16x16x32_f16(a0, b0, acc[0][0], 0, 0, 0);
    acc[0][1] = __builtin_amdgcn_mfma_f32_16x16x32_f16(a0, b1, acc[0][1], 0, 0, 0);
    acc[1][0] = __builtin_amdgcn_mfma_f32_16x16x32_f16(a1, b0, acc[1][0], 0, 0, 0);
    acc[1][1] = __builtin_amdgcn_mfma_f32_16x16x32_f16(a1, b1, acc[1][1], 0, 0, 0);
  }
  if constexpr (EPI == 0) {
    #pragma unroll
    for (int r = 0; r < 2; ++r)
      #pragma unroll
      for (int c = 0; c < 2; ++c) {
        int rowb = w * 32 + r * 16 + ((lane >> 4) << 2);
        int n = nb + c * 16 + (lane & 15);
        #pragma unroll
        for (int j = 0; j < 4; ++j)
          out[(size_t)(rowb + j) * NN + n] = acc[r][c][j] + bias[rowb + j];
      }
  } else if constexpr (EPI == 3) {
    #pragma unroll
    for (int r = 0; r < 2; ++r)
      #pragma unroll
      for (int c = 0; c < 2; ++c) {
        int rowb = w * 32 + r * 16 + ((lane >> 4) << 2);
        int n = nb + c * 16 + (lane & 15);
        float ss = 1e-6f;
        #pragma unroll
        for (int j = 0; j < 4; ++j) {
          float v = acc[r][c][j] + bias[rowb + j];
          ss += v * v;
        }
        out[(size_t)(rowb >> 2) * NN + n] = sqrtf(ss);
      }
  } else {
    __shared__ float tile[128][33];
    #pragma unroll
    for (int r = 0; r < 2; ++r)
      #pragma unroll
      for (int c = 0; c < 2; ++c) {
        int rowb = w * 32 + r * 16 + ((lane >> 4) << 2);
        int col = c * 16 + (lane & 15);
        #pragma unroll
        for (int j = 0; j < 4; ++j) tile[rowb + j][col] = acc[r][c][j];
      }
    __syncthreads();
    if constexpr (EPI == 1) {
      #pragma unroll
      for (int h = 0; h < 2; ++h) {
        int nl = (t & 15) + h * 16;
        int q = t >> 4;
        float v[8];
        #pragma unroll
        for (int j = 0; j < 8; ++j) v[j] = tile[q * 8 + j][nl] + bias[q * 8 + j];
        #pragma unroll
        for (int half = 0; half < 2; ++half) {
          float ss = 0.f;
          #pragma unroll
          for (int j = 0; j < 4; ++j) { float z = v[half * 4 + j]; ss += z * z; }
          float inv = 1.f / (sqrtf(ss) + 1e-6f);
          #pragma unroll
          for (int j = 0; j < 4; ++j) v[half * 4 + j] *= inv;
        }
        f16x8 fr;
        #pragma unroll
        for (int j = 0; j < 8; ++j) {
          out[(size_t)(q * 8 + j) * NN + nb + nl] = v[j];
          fr[j] = (f16)v[j];
        }
        *(f16x8*)(ofrag + nfrag_off(q * 8, nb + nl)) = fr;
      }
    } else {  // EPI == 2: Z adj-frags
      #pragma unroll
      for (int h = 0; h < 2; ++h) {
        int o = t & 127;
        int noct = (t >> 7) + h * 2;
        f16x8 fr;
        #pragma unroll
        for (int j = 0; j < 8; ++j) fr[j] = (f16)tile[o][noct * 8 + j];
        *(f16x8*)(ofrag + frag_off(8, o, nb + noct * 8)) = fr;
      }
    }
  }
}

// ---------------- reduce split-K + cy -> c ; per-(ch,quarter) stats partials ----------
// part layout: [z][rt][128][16]; 512 blocks: ch = b>>2, quarter qa = b&3 (1024 nodes)
__global__ __launch_bounds__(256)
void reduce_stats(const float* __restrict__ part, const float* __restrict__ cy,
                  float* __restrict__ c, float* __restrict__ statp) {
  const int b = blockIdx.x;
  const int ch = b >> 2, qa = b & 3;
  const int t = threadIdx.x;
  const int lane = t & 63, w = t >> 6;
  const int n0 = qa * 1024 + t * 4;
  const size_t poff = (((size_t)(n0 >> 4)) * 128 + ch) * 16 + (n0 & 15);
  const size_t pstride = (size_t)256 * 128 * 16;
  f4 v = *(const f4*)(cy + (size_t)ch * NN + n0);
  #pragma unroll
  for (int z = 0; z < 8; ++z) {
    f4 p = *(const f4*)(part + (size_t)z * pstride + poff);
    v.x += p.x; v.y += p.y; v.z += p.z; v.w += p.w;
  }
  *(f4*)(c + (size_t)ch * NN + n0) = v;
  float s  = v.x + v.y + v.z + v.w;
  float ss = v.x*v.x + v.y*v.y + v.z*v.z + v.w*v.w;
  #pragma unroll
  for (int off = 32; off > 0; off >>= 1) { s += __shfl_down(s, off); ss += __shfl_down(ss, off); }
  __shared__ float rs[4], rss[4];
  if (lane == 0) { rs[w] = s; rss[w] = ss; }
  __syncthreads();
  if (t == 0) {
    statp[(ch * 4 + qa) * 2]     = rs[0] + rs[1] + rs[2] + rs[3];
    statp[(ch * 4 + qa) * 2 + 1] = rss[0] + rss[1] + rss[2] + rss[3];
  }
}

// ---------------- fused: GN stats fin + Kuramoto update + Z = Wc @ x4_new (per-block) ------
__global__ __launch_bounds__(256)
void kur_fin(const float* __restrict__ cb, const float* __restrict__ statp,
             const float* __restrict__ gng, const float* __restrict__ gnb,
             const f16* __restrict__ wcfrag, float* __restrict__ x4,
             f16* __restrict__ x4frag, f16* __restrict__ zfrag) {
  __shared__ float lds[2664];
  f16* bf = (f16*)lds;                  // 4 k-tiles x 512 f16 (x4-new B-frags)
  f16* zt = (f16*)(lds + 1024);         // 128 x 24 f16 (Z tile)
  float* gmu = lds + 2600;
  float* grs = lds + 2632;
  const int t = threadIdx.x;
  const int lane = t & 63, w = t >> 6;
  if (t < 32) {
    float s = 0.f, ss = 0.f;
    #pragma unroll
    for (int o = 0; o < 4; ++o)
      #pragma unroll
      for (int qa = 0; qa < 4; ++qa) {
        s  += statp[((4 * t + o) * 4 + qa) * 2];
        ss += statp[((4 * t + o) * 4 + qa) * 2 + 1];
      }
    float mu = s * (1.f / 16384.f);
    float var = ss * (1.f / 16384.f) - mu * mu;
    gmu[t] = mu;
    grs[t] = rsqrtf(var + 1e-5f);
  }
  __syncthreads();
  const int nb = blockIdx.x * 16;
  const int n = nb + (t & 15);
  const int q16 = t >> 4;
  float res[8];
  #pragma unroll
  for (int gi = 0; gi < 2; ++gi) {
    const int g = 2 * q16 + gi;
    const float mu = gmu[g], rstd = grs[g];
    float cn[4], xo[4];
    float inner = 0.f;
    #pragma unroll
    for (int o = 0; o < 4; ++o) {
      const int chn = 4 * g + o;
      float cv = (cb[(size_t)chn * NN + n] - mu) * rstd * gng[chn] + gnb[chn];
      float xv = x4[(size_t)chn * NN + n];
      cn[o] = cv; xo[o] = xv; inner += cv * xv;
    }
    float ssq = 0.f, xn[4];
    #pragma unroll
    for (int o = 0; o < 4; ++o) {
      xn[o] = xo[o] + (cn[o] - inner * xo[o]);
      ssq += xn[o] * xn[o];
    }
    float inv = 1.f / (sqrtf(ssq) + 1e-6f);
    #pragma unroll
    for (int o = 0; o < 4; ++o) {
      float vv = xn[o] * inv;
      res[gi * 4 + o] = vv;
      x4[(size_t)(4 * g + o) * NN + n] = vv;
    }
  }
  {
    f16x8 fr;
    #pragma unroll
    for (int j = 0; j < 8; ++j) fr[j] = (f16)res[j];
    *(f16x8*)(bf + (q16 >> 2) * 512 + (((n & 15) + 16 * (q16 & 3)) << 3)) = fr;
  }
  __syncthreads();
  // x4 n-frags (always)
  {
    const int kt = t >> 6, s2 = t & 63;
    *(f16x8*)(x4frag + ((size_t)kt * 256 + (nb >> 4)) * 512 + s2 * 8)
        = *(const f16x8*)(bf + kt * 512 + s2 * 8);
  }
  if (!zfrag) return;
  // Z = Wc @ x4_new  (wave w: output rows 32w..32w+31)
  f32x4v za0 = (f32x4v){0,0,0,0}, za1 = (f32x4v){0,0,0,0};
  #pragma unroll
  for (int kt = 0; kt < 4; ++kt) {
    f16x8 a0 = *(const f16x8*)(wcfrag + ((size_t)(2 * w) * 4 + kt) * 512 + lane * 8);
    f16x8 a1 = *(const f16x8*)(wcfrag + ((size_t)(2 * w + 1) * 4 + kt) * 512 + lane * 8);
    f16x8 bv = *(const f16x8*)(bf + kt * 512 + lane * 8);
    za0 = __builtin_amdgcn_mfma_f32_16x16x32_f16(a0, bv, za0, 0, 0, 0);
    za1 = __builtin_amdgcn_mfma_f32_16x16x32_f16(a1, bv, za1, 0, 0, 0);
  }
  const int colz = lane & 15;
  const int rz = (lane >> 4) << 2;
  #pragma unroll
  for (int j = 0; j < 4; ++j) {
    zt[(w * 32 + rz + j) * 24 + colz]      = (f16)za0[j];
    zt[(w * 32 + 16 + rz + j) * 24 + colz] = (f16)za1[j];
  }
  __syncthreads();
  {
    const int ch = t & 127, noct = t >> 7;
    f16x8 fr = *(const f16x8*)(zt + ch * 24 + noct * 8);
    const int nn2 = nb + noct * 8;
    *(f16x8*)(zfrag + ((size_t)(nn2 >> 5) * 8 + (ch >> 4)) * 512
                    + (((ch & 15) + 16 * ((nn2 & 31) >> 3)) << 3)) = fr;
  }
}

// ---------------- fused readout tail: logits = (out_w @ ro_w2) @ mag + fused bias ----------
__global__ void head(const float* __restrict__ mag, const float* __restrict__ rw2,
                     const float* __restrict__ rb2, const float* __restrict__ ow,
                     const float* __restrict__ ob, float* __restrict__ out) {
  __shared__ float fw[4][32];
  __shared__ float fb[4];
  const int t = threadIdx.x;
  if (t < 128) {
    const int k = t >> 5, m = t & 31;
    float s = 0.f;
    for (int o = 0; o < 128; ++o) s += ow[k * 128 + o] * rw2[o * 32 + m];
    fw[k][m] = s;
  } else if (t < 132) {
    const int k = t - 128;
    float s = ob[k];
    for (int o = 0; o < 128; ++o) s += ow[k * 128 + o] * rb2[o];
    fb[k] = s;
  }
  __syncthreads();
  const int n = blockIdx.x * 256 + t;
  float a0 = fb[0], a1 = fb[1], a2 = fb[2], a3 = fb[3];
  for (int m = 0; m < 32; ++m) {
    float v = mag[(size_t)m * NN + n];
    a0 += fw[0][m] * v; a1 += fw[1][m] * v; a2 += fw[2][m] * v; a3 += fw[3][m] * v;
  }
  f4 r; r.x = a0; r.y = a1; r.z = a2; r.w = a3;
  ((f4*)out)[n] = r;
}

extern "C" void kernel_launch(void* const* d_in, const int* in_sizes, int n_in,
                              void* d_out, int out_size, void* d_ws, size_t ws_size,
                              hipStream_t stream) {
  const float* x      = (const float*)d_in[0];
  const float* adj    = (const float*)d_in[1];
  const float* mc_w0  = (const float*)d_in[2];
  const float* mc_b0  = (const float*)d_in[3];
  const float* mc_w1  = (const float*)d_in[4];
  const float* mc_b1  = (const float*)d_in[5];
  const float* mc_w2  = (const float*)d_in[6];
  const float* mc_b2  = (const float*)d_in[7];
  const float* mc_w3  = (const float*)d_in[8];
  const float* mc_b3  = (const float*)d_in[9];
  const float* proj_w = (const float*)d_in[10];
  const float* proj_b = (const float*)d_in[11];
  const float* pat_w  = (const float*)d_in[12];
  const float* pat_b  = (const float*)d_in[13];
  const float* kur_wc = (const float*)d_in[14];
  const float* kur_bc = (const float*)d_in[15];
  const float* kur_wy = (const float*)d_in[16];
  const float* kur_by = (const float*)d_in[17];
  const float* gn_g   = (const float*)d_in[18];
  const float* gn_b   = (const float*)d_in[19];
  const float* ro_w1  = (const float*)d_in[20];
  const float* ro_b1  = (const float*)d_in[21];
  const float* ro_w2  = (const float*)d_in[22];
  const float* ro_b2  = (const float*)d_in[23];
  const float* out_w  = (const float*)d_in[24];
  const float* out_b  = (const float*)d_in[25];
  float* out = (float*)d_out;
  float* Wf = (float*)d_ws;

  // ---- workspace layout (float-word offsets); ~84 MB (d_ws is 256 MiB per harness fill) --
  f16*   adj16    = (f16*)d_ws;                  // 32 MB
  float* csp      = Wf + 8388608;                // colsum partials (4 MB region)
  f16*   fragN    = (f16*)(Wf + 10485760);       // 3.5 MB (im2col, then gst frags)
  f16*   fragA    = (f16*)(Wf + 11403264);       // 0.5 MB
  f16*   fragB    = (f16*)(Wf + 11534336);       // 1 MB
  float* xT       = Wf + 11796480;               // 1 MB
  float* A1       = Wf + 12058624;               // 1 MB
  float* A2       = Wf + 12320768;               // 1 MB (magb alias)
  float* s1cat    = Wf + 12582912;               // 2 MB
  float* B1       = Wf + 13107200;               // 2 MB (wpart/Weff alias, early)
  float* wpart    = B1;
  float* Weff     = Wf + 13238272;
  float* B2       = Wf + 13631488;               // 2 MB
  float* gstf     = Wf + 14155776;               // 7 MB; alias after gst2frag:
  float* cbuf     = gstf;                        //   2 MB
  float* x4       = Wf + 14680064;               // 2 MB
  f16*   x4frag   = (f16*)(Wf + 15204352);       // 1 MB
  float* cy       = Wf + 15990784;               // 2 MB
  f16*   zfrag    = (f16*)(Wf + 16515072);       // 1 MB
  f16*   wcyfrag  = (f16*)(Wf + 16777216);       // 112 KB
  f16*   patfrag  = (f16*)(Wf + 16805888);       // 112 KB
  f16*   wcfrag   = (f16*)(Wf + 16834560);       // 32 KB
  f16*   row1frag = (f16*)(Wf + 16842752);       // 32 KB
  float* deg      = Wf + 16850944;               // 16 KB
  float* beff     = Wf + 16855040;               // 128
  float* cyb      = Wf + 16855168;               // 128
  float* statp    = Wf + 16855296;               // 4 KB (128 ch x 4 quarters x 2)
  float* part     = Wf + 17039360;               // 16 MB split-K partials (new layout)
  float* magb     = A2;

  dim3 b256(256);

  // 1. adj -> fp16 A-frags + degree
  convert_cs2<<<dim3(128, 8), b256, 0, stream>>>(adj, adj16, csp);
  colsum_fin<<<dim3(16), b256, 0, stream>>>(csp, deg);

  // 2. weight folds
  wfold1<<<dim3(16), b256, 0, stream>>>(proj_w, mc_w0, mc_w1, mc_w2, mc_w3, wpart);
  wfold_asm<<<dim3(32), b256, 0, stream>>>(wpart, proj_w, proj_b,
                                           mc_b0, mc_b1, mc_b2, mc_b3, Weff, beff);
  wfold2<<<dim3(14), b256, 0, stream>>>(kur_wy, Weff, beff, kur_by, kur_bc, wcyfrag, cyb);
  wprep<<<dim3(352), b256, 0, stream>>>(pat_w, kur_wc, ro_w1, patfrag, wcfrag, row1frag);

  // 3. x transpose + frags; im2col; cy = conv(x, Wcy) + cyb
  transpose_x<<<dim3(64), b256, 0, stream>>>(x, deg, xT, gstf, fragA);
  im2col<<<dim3(896), b256, 0, stream>>>(x, fragN);
  wgemm<14, 0><<<dim3(128), b256, 0, stream>>>(wcyfrag, fragN, cyb, cy, nullptr);

  // 4. GST first order (F=64, KZ=16; 1024 blocks, shared-B waves)
  adjmm16<64, 16><<<dim3(1024), b256, 0, stream>>>(adj16, fragA, part);
  reduce_P<<<dim3(256), b256, 0, stream>>>(part, xT, xT, A1, fragA, 4,
                                           fragB, 0, gstf, 1, 1, s1cat, deg, 64, 16);
  adjmm16<64, 16><<<dim3(1024), b256, 0, stream>>>(adj16, fragA, part);
  reduce_P<<<dim3(256), b256, 0, stream>>>(part, A1, A1, A2, fragA, 4,
                                           fragB, 64, gstf, 2, 2, s1cat + (size_t)64 * NN, deg, 64, 16);
  adjmm16<64, 16><<<dim3(1024), b256, 0, stream>>>(adj16, fragA, part);
  reduce_P<<<dim3(256), b256, 0, stream>>>(part, A2, nullptr, A1, fragA, 4,
                                           nullptr, 0, nullptr, -1, -1, nullptr, deg, 64, 16);
  adjmm16<64, 16><<<dim3(1024), b256, 0, stream>>>(adj16, fragA, part);
  reduce_P<<<dim3(256), b256, 0, stream>>>(part, A1, A2, A1, nullptr, 4,
                                           nullptr, 0, gstf, 3, 3, nullptr, deg, 64, 16);

  // 5. GST second order (F=128, KZ=8; 512 blocks, shared-B waves)
  adjmm16<128, 8><<<dim3(512), b256, 0, stream>>>(adj16, fragB, part);
  reduce_P<<<dim3(512), b256, 0, stream>>>(part, s1cat, nullptr, B1, fragB, 8,
                                           nullptr, 0, nullptr, -1, -1, nullptr, deg, 128, 8);
  adjmm16<128, 8><<<dim3(512), b256, 0, stream>>>(adj16, fragB, part);
  reduce_P<<<dim3(512), b256, 0, stream>>>(part, B1, B1, B2, fragB, 8,
                                           nullptr, 0, gstf, 4, -1, nullptr, deg, 128, 8);
  adjmm16<128, 8><<<dim3(512), b256, 0, stream>>>(adj16, fragB, part);
  reduce_P<<<dim3(512), b256, 0, stream>>>(part, B2, nullptr, B1, fragB, 8,
                                           nullptr, 0, nullptr, -1, -1, nullptr, deg, 128, 8);
  adjmm16<128, 8><<<dim3(512), b256, 0, stream>>>(adj16, fragB, part);
  reduce_P<<<dim3(512), b256, 0, stream>>>(part, B1, B2, B1, nullptr, 8,
                                           nullptr, 0, gstf, 5, 6, nullptr, deg, 128, 8);

  // 6. gst -> n-frags; x0 GEMM + osc-norm; Z0
  gst2frag<<<dim3(64, 7), b256, 0, stream>>>(gstf, fragN);
  wgemm<14, 1><<<dim3(128), b256, 0, stream>>>(patfrag, fragN, pat_b, x4, x4frag);
  wgemm<4, 2><<<dim3(128), b256, 0, stream>>>(wcfrag, x4frag, nullptr, nullptr, zfrag);

  // 7. Kuramoto dynamics: 3 kernels/iter; last iter skips Z emission
  for (int q = 0; q < 8; ++q) {
    adjmm16<128, 8><<<dim3(512), b256, 0, stream>>>(adj16, zfrag, part);
    reduce_stats<<<dim3(512), b256, 0, stream>>>(part, cy, cbuf, statp);
    kur_fin<<<dim3(256), b256, 0, stream>>>(cbuf, statp, gn_g, gn_b, wcfrag,
                                            x4, x4frag, (q < 7) ? zfrag : nullptr);
  }

  // 8. readout magnitude + fused head
  wgemm<4, 3><<<dim3(128), b256, 0, stream>>>(row1frag, x4frag, ro_b1, magb, nullptr);
  head<<<dim3(16), b256, 0, stream>>>(magb, ro_w2, ro_b2, out_w, out_b, out);
}

// Round 12
// 466.534 us; speedup vs baseline: 1.2320x; 1.2320x over previous
//
#include <hip/hip_runtime.h>
#include <math.h>

#define NN 4096

typedef float4 f4;
typedef _Float16 f16;
typedef _Float16 f16x8 __attribute__((ext_vector_type(8)));
typedef _Float16 h4 __attribute__((ext_vector_type(4)));
typedef float f32x4v __attribute__((ext_vector_type(4)));

// adjmm-convention B-frag offset (f16 units): ch = output column, n = reduction (node)
__device__ __forceinline__ size_t frag_off(int CT, int ch, int n) {
  return ((size_t)(n >> 5) * CT + (ch >> 4)) * 512
       + (size_t)((((ch & 15) + (((n & 31) >> 3) << 4)) << 3) + (n & 7));
}
// n-convention B-frag (for wgemm): col = node n (4096 wide -> CT=256), k = feature
__device__ __forceinline__ size_t nfrag_off(int k, int n) {
  return ((size_t)(k >> 5) * 256 + (n >> 4)) * 512
       + (size_t)((((n & 15) + (((k & 31) >> 3) << 4)) << 3) + (k & 7));
}
// A-frag offset (weights, M=128): row o, reduction k
__device__ __forceinline__ size_t afrag_off(int K32, int o, int k) {
  return ((size_t)(o >> 4) * K32 + (k >> 5)) * 512
       + (size_t)((((o & 15) + (((k & 31) >> 3) << 4)) << 3) + (k & 7));
}

// ---------------- adj fp32 -> fp16 A-frags (LDS-staged, coalesced) + colsum partials -------
__global__ __launch_bounds__(256)
void convert_cs2(const float* __restrict__ adj, f16* __restrict__ adj16,
                 float* __restrict__ csp) {
  __shared__ f16 lds16[32][520];
  const int rb = blockIdx.x;        // 128 blocks of 32 rows
  const int cb = blockIdx.y;        // 8 col blocks of 512
  const int t = threadIdx.x;
  const int half = t >> 7;          // 2 row halves of 16
  const int u = t & 127;
  const int c0 = cb * 512 + u * 4;
  float cs0 = 0.f, cs1 = 0.f, cs2 = 0.f, cs3 = 0.f;
  #pragma unroll 4
  for (int r = 0; r < 16; ++r) {
    const int i = rb * 32 + half * 16 + r;
    f4 v = *(const f4*)(adj + (size_t)i * NN + c0);
    cs0 += v.x; cs1 += v.y; cs2 += v.z; cs3 += v.w;
    h4 hv; hv[0] = (f16)v.x; hv[1] = (f16)v.y; hv[2] = (f16)v.z; hv[3] = (f16)v.w;
    *(h4*)&lds16[half * 16 + r][u * 4] = hv;
  }
  f4 cv; cv.x = cs0; cv.y = cs1; cv.z = cs2; cv.w = cs3;
  *(f4*)(csp + (size_t)(rb * 2 + half) * NN + c0) = cv;
  __syncthreads();
  const int rt = rb * 2 + half;
  f16* dst = adj16 + ((size_t)rt * 128 + cb * 16) * 512;
  #pragma unroll
  for (int s = 0; s < 8; ++s) {
    const int e = s * 1024 + u * 8;
    const int bl = e >> 9;
    const int l = (e >> 3) & 63;
    const int row = half * 16 + (l & 15);
    const int col = bl * 32 + (l >> 4) * 8;
    f16x8 fr = *(const f16x8*)&lds16[row][col];
    *(f16x8*)(dst + e) = fr;
  }
}

__global__ void colsum_fin(const float* __restrict__ csp, float* __restrict__ deg_inv) {
  int j = blockIdx.x * 256 + threadIdx.x;
  float s = 0.f;
  for (int rb = 0; rb < 256; ++rb) s += csp[(size_t)rb * NN + j];
  deg_inv[j] = 1.0f / (s + 1e-6f);
}

// ---------------- weight fold 1: per (branch, tap) GEMM into wpart ----------------
__global__ __launch_bounds__(256)
void wfold1(const float* __restrict__ proj_w,
            const float* __restrict__ w0, const float* __restrict__ w1,
            const float* __restrict__ w2, const float* __restrict__ w3,
            float* __restrict__ wpart) {
  __shared__ float projs[128][65];
  __shared__ float wk[64][65];
  const int b = blockIdx.x;
  int br, kp;
  if (b == 0) { br = 0; kp = 0; }
  else if (b < 4) { br = 1; kp = b - 1; }
  else if (b < 9) { br = 2; kp = b - 4; }
  else { br = 3; kp = b - 9; }
  const int Kbr = 2 * br + 1;
  const float* Wbr = (br == 0) ? w0 : (br == 1) ? w1 : (br == 2) ? w2 : w3;
  const int baseo[4] = {0, 8192, 32768, 73728};
  const int t = threadIdx.x;
  #pragma unroll
  for (int r = 0; r < 32; ++r) {
    int e = r * 256 + t; int o = e >> 6, cp = e & 63;
    projs[o][cp] = proj_w[(size_t)o * 256 + br * 64 + cp];
  }
  #pragma unroll
  for (int r = 0; r < 16; ++r) {
    int e = r * 256 + t; int cp = e >> 6, c = e & 63;
    wk[cp][c] = Wbr[(size_t)(cp * 64 + c) * Kbr + kp];
  }
  __syncthreads();
  for (int i = 0; i < 32; ++i) {
    int e = i * 256 + t; int o = e >> 6, c = e & 63;
    float s = 0.f;
    #pragma unroll 8
    for (int cp = 0; cp < 64; ++cp) s += projs[o][cp] * wk[cp][c];
    wpart[baseo[br] + (size_t)(o * 64 + c) * Kbr + kp] = s;
  }
}

// ---------------- weight fold assemble: Weff[o][c][7] + beff ----------------
__global__ void wfold_asm(const float* __restrict__ wpart, const float* __restrict__ proj_w,
                          const float* __restrict__ proj_b,
                          const float* __restrict__ b0, const float* __restrict__ b1,
                          const float* __restrict__ b2, const float* __restrict__ b3,
                          float* __restrict__ Weff, float* __restrict__ beff) {
  const int id = blockIdx.x * 256 + threadIdx.x;
  const int o = id >> 6, c = id & 63;
  const int oc = o * 64 + c;
  #pragma unroll
  for (int k = 0; k < 7; ++k) {
    float s = 0.f;
    if (k == 3)            s += wpart[oc];
    if (k >= 2 && k <= 4)  s += wpart[8192  + oc * 3 + (k - 2)];
    if (k >= 1 && k <= 5)  s += wpart[32768 + oc * 5 + (k - 1)];
    s += wpart[73728 + oc * 7 + k];
    Weff[(size_t)oc * 7 + k] = s;
  }
  if (blockIdx.x == 0 && threadIdx.x < 128) {
    const int oo = threadIdx.x;
    float s = proj_b[oo];
    for (int j = 0; j < 64; ++j) {
      s += proj_w[(size_t)oo * 256 + j] * b0[j];
      s += proj_w[(size_t)oo * 256 + 64 + j] * b1[j];
      s += proj_w[(size_t)oo * 256 + 128 + j] * b2[j];
      s += proj_w[(size_t)oo * 256 + 192 + j] * b3[j];
    }
    beff[oo] = s;
  }
}

// ---------------- weight fold 2: Wcy = kur_wy @ Weff -> f16 A-frags; cyb ----------------
__global__ __launch_bounds__(256)
void wfold2(const float* __restrict__ kur_wy, const float* __restrict__ Weff,
            const float* __restrict__ beff, const float* __restrict__ kur_by,
            const float* __restrict__ kur_bc,
            f16* __restrict__ wcyfrag, float* __restrict__ cyb) {
  __shared__ float wyh[128][65];
  __shared__ float weffL[128][33];
  const int ckb = blockIdx.x * 32;
  const int t = threadIdx.x;
  const int o = t & 127, hh = t >> 7;
  #pragma unroll
  for (int r = 0; r < 16; ++r) {
    int e = r * 256 + t; int op = e >> 5, ck = e & 31;
    weffL[op][ck] = Weff[(size_t)op * 448 + ckb + ck];
  }
  float acc[16];
  #pragma unroll
  for (int i = 0; i < 16; ++i) acc[i] = 0.f;
  float bacc = 0.f;
  for (int h = 0; h < 2; ++h) {
    __syncthreads();
    #pragma unroll
    for (int r = 0; r < 32; ++r) {
      int e = r * 256 + t; int oo = e >> 6, o2 = e & 63;
      wyh[oo][o2] = kur_wy[(size_t)oo * 128 + h * 64 + o2];
    }
    __syncthreads();
    for (int oo = 0; oo < 64; ++oo) {
      float w = wyh[o][oo];
      int op = h * 64 + oo;
      #pragma unroll
      for (int i = 0; i < 16; ++i) acc[i] += w * weffL[op][hh * 16 + i];
      if (t < 128) bacc += w * beff[op];
    }
  }
  #pragma unroll
  for (int i = 0; i < 16; ++i) {
    int ck = ckb + hh * 16 + i;
    int c = ck / 7, kt = ck % 7;
    wcyfrag[afrag_off(14, o, kt * 64 + c)] = (f16)acc[i];
  }
  if (blockIdx.x == 0 && t < 128) cyb[t] = bacc + kur_by[t] + kur_bc[t];
}

// ---------------- convert pat_w / kur_wc / ro_w1 to f16 A-frags ----------------
__global__ void wprep(const float* __restrict__ pat_w, const float* __restrict__ kur_wc,
                      const float* __restrict__ ro_w1,
                      f16* __restrict__ patfrag, f16* __restrict__ wcfrag,
                      f16* __restrict__ row1frag) {
  const int id = blockIdx.x * 256 + threadIdx.x;
  if (id < 57344) {
    int o = id / 448, k = id % 448;
    patfrag[afrag_off(14, o, k)] = (f16)pat_w[id];
  } else if (id < 73728) {
    int e = id - 57344; int o = e >> 7, k = e & 127;
    wcfrag[afrag_off(4, o, k)] = (f16)kur_wc[e];
  } else {
    int e = id - 73728; int o = e >> 7, k = e & 127;
    row1frag[afrag_off(4, o, k)] = (f16)ro_w1[e];
  }
}

// ---------------- x[N,64] -> xT[64][N] + gst coef0 row + fragA (x*deg_inv) ----------------
__global__ void transpose_x(const float* __restrict__ x, const float* __restrict__ deg,
                            float* __restrict__ xT, float* __restrict__ gst,
                            f16* __restrict__ fragA) {
  __shared__ float T[64][65];
  const int nb = blockIdx.x * 64;
  const int t = threadIdx.x;
  #pragma unroll
  for (int r = 0; r < 16; ++r) {
    int e = r * 256 + t; int nl = e >> 6, f = e & 63;
    T[nl][f] = x[(size_t)(nb + nl) * 64 + f];
  }
  __syncthreads();
  #pragma unroll
  for (int r = 0; r < 16; ++r) {
    int e = r * 256 + t; int f = e >> 6, nl = e & 63;
    float v = T[nl][f];
    xT[(size_t)f * NN + nb + nl] = v;
    gst[(size_t)f * 7 * NN + nb + nl] = v;
  }
  #pragma unroll
  for (int k = 0; k < 2; ++k) {
    int fi = k * 256 + t;
    int f = fi >> 3, n0l = (fi & 7) << 3;
    f16x8 fr;
    #pragma unroll
    for (int j = 0; j < 8; ++j) fr[j] = (f16)(T[n0l + j][f] * deg[nb + n0l + j]);
    *(f16x8*)(fragA + frag_off(4, f, nb + n0l)) = fr;
  }
}

// ---------------- im2col: x -> n-frags [k = dk*64+c][n], zero-padded ----------------
__global__ void im2col(const float* __restrict__ x, f16* __restrict__ fragN) {
  const int ot = blockIdx.x * 256 + threadIdx.x;
  const int q = ot >> 12;
  const int n = ot & 4095;
  const int dk = q >> 3;
  const int c0 = (q & 7) * 8;
  const int np = n + dk - 3;
  f16x8 fr;
  if (np >= 0 && np < NN) {
    const float* src = x + (size_t)np * 64 + c0;
    f4 v0 = *(const f4*)src, v1 = *(const f4*)(src + 4);
    fr[0]=(f16)v0.x; fr[1]=(f16)v0.y; fr[2]=(f16)v0.z; fr[3]=(f16)v0.w;
    fr[4]=(f16)v1.x; fr[5]=(f16)v1.y; fr[6]=(f16)v1.z; fr[7]=(f16)v1.w;
  } else {
    #pragma unroll
    for (int j = 0; j < 8; ++j) fr[j] = (f16)0.f;
  }
  *(f16x8*)(fragN + nfrag_off(q * 8, n)) = fr;
}

// ---------------- MFMA split-K GEMM vs adjacency, v3: 16-row tiles, 2-step LDS reduce -----
// block b: rows (b&255)*16..+16, K-chunk kz = b>>8; 4 waves split the block's K-range.
// LDS = 2*CT*256 floats (16 KB for F=128, 8 KB for F=64) -> 4-8 blocks/CU, 16-32 waves/CU.
template<int F, int KZ>
__global__ __launch_bounds__(256)
void adjmm16(const f16* __restrict__ adj16, const f16* __restrict__ rhs,
             float* __restrict__ part) {
  constexpr int CT = F / 16;
  constexpr int KSB = (NN / KZ) / 32;   // K-steps per block
  constexpr int KS = KSB / 4;           // K-steps per wave
  const int t = threadIdx.x;
  const int lane = t & 63, w = t >> 6;
  const int mt = blockIdx.x & 255;      // 16-row tile
  const int kz = blockIdx.x >> 8;
  const int kt0 = kz * KSB + w * KS;
  const size_t aoff = ((size_t)mt * 128 + kt0) * 512 + (size_t)lane * 8;
  const f16* bb = rhs + (size_t)kt0 * CT * 512 + lane * 8;
  f32x4v acc[CT];
  #pragma unroll
  for (int c = 0; c < CT; ++c) acc[c] = (f32x4v){0.f, 0.f, 0.f, 0.f};
  #pragma unroll 2
  for (int i = 0; i < KS; ++i) {
    f16x8 a = *(const f16x8*)(adj16 + aoff + (size_t)i * 512);
    #pragma unroll
    for (int c = 0; c < CT; ++c) {
      f16x8 bv = *(const f16x8*)(bb + ((size_t)i * CT + c) * 512);
      acc[c] = __builtin_amdgcn_mfma_f32_16x16x32_f16(a, bv, acc[c], 0, 0, 0);
    }
  }
  __shared__ float redf[2 * CT * 256];
  // step 1: waves 2,3 store
  if (w >= 2) {
    float* myw = redf + (w - 2) * (CT * 256);
    #pragma unroll
    for (int c = 0; c < CT; ++c) *(f32x4v*)(myw + c * 256 + lane * 4) = acc[c];
  }
  __syncthreads();
  // step 2: waves 0,1 add partner (w+2) and store
  if (w < 2) {
    float* myw = redf + w * (CT * 256);
    #pragma unroll
    for (int c = 0; c < CT; ++c) {
      acc[c] += *(const f32x4v*)(myw + c * 256 + lane * 4);
      *(f32x4v*)(myw + c * 256 + lane * 4) = acc[c];
    }
  }
  __syncthreads();
  float* pb = part + (size_t)kz * F * NN;
  constexpr int SLOTS = CT * 64;        // f4 slots (16 nodes x F ch / 4)
  #pragma unroll
  for (int s = 0; s < SLOTS; s += 256) {
    const int slot = s + t;
    f32x4v v = *(const f32x4v*)(redf + slot * 4);
    v += *(const f32x4v*)(redf + CT * 256 + slot * 4);
    const int ct = slot >> 6, l = slot & 63;
    const int ch = ct * 16 + (l & 15);
    const int node0 = mt * 16 + ((l >> 4) << 2);
    *(f32x4v*)(pb + (size_t)ch * NN + node0) = v;
  }
}

// ---------------- reduce split-K + P epilogue + frag/diff/gst/s1 fusion (f4/thread) -------
__global__ void reduce_P(const float* __restrict__ part, const float* __restrict__ u,
                         const float* __restrict__ D, float* __restrict__ outp,
                         f16* __restrict__ fragNext, int nextCT,
                         f16* __restrict__ fragDiff, int diffChOff,
                         float* __restrict__ gstf, int coefLo, int coefHi,
                         float* __restrict__ s1buf, const float* __restrict__ deg,
                         int F, int KZ) {
  const int id = blockIdx.x * 256 + threadIdx.x;
  const int ch = id >> 10, n0 = (id & 1023) << 2;
  const size_t base = (size_t)ch * NN + n0;
  float a0 = 0.f, a1 = 0.f, a2 = 0.f, a3 = 0.f;
  for (int z = 0; z < KZ; ++z) {
    f4 p = *(const f4*)(part + (size_t)z * F * NN + base);
    a0 += p.x; a1 += p.y; a2 += p.z; a3 += p.w;
  }
  f4 u0 = *(const f4*)(u + base);
  float o0 = 0.5f * (u0.x + a0), o1 = 0.5f * (u0.y + a1);
  float o2 = 0.5f * (u0.z + a2), o3 = 0.5f * (u0.w + a3);
  f4 ov; ov.x = o0; ov.y = o1; ov.z = o2; ov.w = o3;
  *(f4*)(outp + base) = ov;
  if (fragNext) {
    f4 dg = *(const f4*)(deg + n0);
    h4 fr;
    fr[0] = (f16)(o0 * dg.x); fr[1] = (f16)(o1 * dg.y);
    fr[2] = (f16)(o2 * dg.z); fr[3] = (f16)(o3 * dg.w);
    *(h4*)(fragNext + frag_off(nextCT, ch, n0)) = fr;
  }
  if (D) {
    f4 d0 = *(const f4*)(D + base);
    float e0 = fabsf(d0.x - o0), e1 = fabsf(d0.y - o1);
    float e2 = fabsf(d0.z - o2), e3 = fabsf(d0.w - o3);
    f4 ev; ev.x = e0; ev.y = e1; ev.z = e2; ev.w = e3;
    if (s1buf) *(f4*)(s1buf + base) = ev;
    if (fragDiff) {
      f4 dg = *(const f4*)(deg + n0);
      h4 fr;
      fr[0] = (f16)(e0 * dg.x); fr[1] = (f16)(e1 * dg.y);
      fr[2] = (f16)(e2 * dg.z); fr[3] = (f16)(e3 * dg.w);
      *(h4*)(fragDiff + frag_off(8, diffChOff + ch, n0)) = fr;
    }
    if (gstf) {
      int coef = (ch < 64) ? coefLo : coefHi;
      if (coef >= 0)
        *(f4*)(gstf + (size_t)((ch & 63) * 7 + coef) * NN + n0) = ev;
    }
  }
}

// ---------------- gstf fp32 rows -> n-frags (LDS transpose) ----------------
__global__ void gst2frag(const float* __restrict__ gstf, f16* __restrict__ fragN) {
  __shared__ float T[64][65];
  const int nb = blockIdx.x * 64;
  const int kb = blockIdx.y * 64;
  const int t = threadIdx.x;
  #pragma unroll
  for (int r = 0; r < 16; ++r) {
    int e = r * 256 + t; int row = e >> 6, col = e & 63;
    T[row][col] = gstf[(size_t)(kb + row) * NN + nb + col];
  }
  __syncthreads();
  #pragma unroll
  for (int h = 0; h < 2; ++h) {
    int idx = h * 256 + t;
    int q = idx >> 6, n = idx & 63;
    f16x8 fr;
    #pragma unroll
    for (int j = 0; j < 8; ++j) fr[j] = (f16)T[q * 8 + j][n];
    *(f16x8*)(fragN + nfrag_off(kb + q * 8, nb + n)) = fr;
  }
}

// ---------------- generic MFMA wgemm (EPI 0/1/2/3 as before) ----------------
template<int K32, int EPI>
__global__ __launch_bounds__(256)
void wgemm(const f16* __restrict__ A, const f16* __restrict__ B,
           const float* __restrict__ bias, float* __restrict__ out,
           f16* __restrict__ ofrag) {
  const int t = threadIdx.x;
  const int lane = t & 63, w = t >> 6;
  const int nb = blockIdx.x * 32;
  const size_t a0b = ((size_t)(2 * w) * K32) * 512 + lane * 8;
  const size_t a1b = ((size_t)(2 * w + 1) * K32) * 512 + lane * 8;
  const size_t b0b = (size_t)(nb >> 4) * 512 + lane * 8;
  f32x4v acc[2][2];
  acc[0][0] = (f32x4v){0,0,0,0}; acc[0][1] = (f32x4v){0,0,0,0};
  acc[1][0] = (f32x4v){0,0,0,0}; acc[1][1] = (f32x4v){0,0,0,0};
  #pragma unroll
  for (int i = 0; i < K32; ++i) {
    f16x8 a0 = *(const f16x8*)(A + a0b + (size_t)i * 512);
    f16x8 a1 = *(const f16x8*)(A + a1b + (size_t)i * 512);
    f16x8 b0 = *(const f16x8*)(B + b0b + (size_t)i * 256 * 512);
    f16x8 b1 = *(const f16x8*)(B + b0b + (size_t)i * 256 * 512 + 512);
    acc[0][0] = __builtin_amdgcn_mfma_f32_16x16x32_f16(a0, b0, acc[0][0], 0, 0, 0);
    acc[0][1] = __builtin_amdgcn_mfma_f32_16x16x32_f16(a0, b1, acc[0][1], 0, 0, 0);
    acc[1][0] = __builtin_amdgcn_mfma_f32_16x16x32_f16(a1, b0, acc[1][0], 0, 0, 0);
    acc[1][1] = __builtin_amdgcn_mfma_f32_16x16x32_f16(a1, b1, acc[1][1], 0, 0, 0);
  }
  if constexpr (EPI == 0) {
    #pragma unroll
    for (int r = 0; r < 2; ++r)
      #pragma unroll
      for (int c = 0; c < 2; ++c) {
        int rowb = w * 32 + r * 16 + ((lane >> 4) << 2);
        int n = nb + c * 16 + (lane & 15);
        #pragma unroll
        for (int j = 0; j < 4; ++j)
          out[(size_t)(rowb + j) * NN + n] = acc[r][c][j] + bias[rowb + j];
      }
  } else if constexpr (EPI == 3) {
    #pragma unroll
    for (int r = 0; r < 2; ++r)
      #pragma unroll
      for (int c = 0; c < 2; ++c) {
        int rowb = w * 32 + r * 16 + ((lane >> 4) << 2);
        int n = nb + c * 16 + (lane & 15);
        float ss = 1e-6f;
        #pragma unroll
        for (int j = 0; j < 4; ++j) {
          float v = acc[r][c][j] + bias[rowb + j];
          ss += v * v;
        }
        out[(size_t)(rowb >> 2) * NN + n] = sqrtf(ss);
      }
  } else {
    __shared__ float tile[128][33];
    #pragma unroll
    for (int r = 0; r < 2; ++r)
      #pragma unroll
      for (int c = 0; c < 2; ++c) {
        int rowb = w * 32 + r * 16 + ((lane >> 4) << 2);
        int col = c * 16 + (lane & 15);
        #pragma unroll
        for (int j = 0; j < 4; ++j) tile[rowb + j][col] = acc[r][c][j];
      }
    __syncthreads();
    if constexpr (EPI == 1) {
      #pragma unroll
      for (int h = 0; h < 2; ++h) {
        int nl = (t & 15) + h * 16;
        int q = t >> 4;
        float v[8];
        #pragma unroll
        for (int j = 0; j < 8; ++j) v[j] = tile[q * 8 + j][nl] + bias[q * 8 + j];
        #pragma unroll
        for (int half = 0; half < 2; ++half) {
          float ss = 0.f;
          #pragma unroll
          for (int j = 0; j < 4; ++j) { float z = v[half * 4 + j]; ss += z * z; }
          float inv = 1.f / (sqrtf(ss) + 1e-6f);
          #pragma unroll
          for (int j = 0; j < 4; ++j) v[half * 4 + j] *= inv;
        }
        f16x8 fr;
        #pragma unroll
        for (int j = 0; j < 8; ++j) {
          out[(size_t)(q * 8 + j) * NN + nb + nl] = v[j];
          fr[j] = (f16)v[j];
        }
        *(f16x8*)(ofrag + nfrag_off(q * 8, nb + nl)) = fr;
      }
    } else {  // EPI == 2: Z adj-frags
      #pragma unroll
      for (int h = 0; h < 2; ++h) {
        int o = t & 127;
        int noct = (t >> 7) + h * 2;
        f16x8 fr;
        #pragma unroll
        for (int j = 0; j < 8; ++j) fr[j] = (f16)tile[o][noct * 8 + j];
        *(f16x8*)(ofrag + frag_off(8, o, nb + noct * 8)) = fr;
      }
    }
  }
}

// ---------------- reduce split-K + cy -> c ; per-(ch,quarter) stats partials -------------
// 512 blocks: ch = b>>2, quarter qa = b&3 (1024 nodes each); round-10 part layout
__global__ __launch_bounds__(256)
void reduce_stats(const float* __restrict__ part, const float* __restrict__ cy,
                  float* __restrict__ c, float* __restrict__ statp) {
  const int b = blockIdx.x;
  const int ch = b >> 2, qa = b & 3;
  const int t = threadIdx.x;
  const int lane = t & 63, w = t >> 6;
  const size_t idx = (size_t)ch * 1024 + qa * 256 + t;   // f4 units
  f4 v = ((const f4*)cy)[idx];
  #pragma unroll
  for (int z = 0; z < 4; ++z) {
    f4 p = ((const f4*)part)[(size_t)z * 131072 + idx];
    v.x += p.x; v.y += p.y; v.z += p.z; v.w += p.w;
  }
  ((f4*)c)[idx] = v;
  float s  = v.x + v.y + v.z + v.w;
  float ss = v.x*v.x + v.y*v.y + v.z*v.z + v.w*v.w;
  #pragma unroll
  for (int off = 32; off > 0; off >>= 1) { s += __shfl_down(s, off); ss += __shfl_down(ss, off); }
  __shared__ float rs[4], rss[4];
  if (lane == 0) { rs[w] = s; rss[w] = ss; }
  __syncthreads();
  if (t == 0) {
    statp[(ch * 4 + qa) * 2]     = rs[0] + rs[1] + rs[2] + rs[3];
    statp[(ch * 4 + qa) * 2 + 1] = rss[0] + rss[1] + rss[2] + rss[3];
  }
}

// ---------------- fused: GN stats fin + Kuramoto update + Z = Wc @ x4_new (per-block) ------
// block b owns 16 nodes; all 128 channels local -> Z-MFMA needs no cross-block data.
// zfrag == nullptr skips the Z computation (last iteration).
__global__ __launch_bounds__(256)
void kur_fin(const float* __restrict__ cb, const float* __restrict__ statp,
             const float* __restrict__ gng, const float* __restrict__ gnb,
             const f16* __restrict__ wcfrag, float* __restrict__ x4,
             f16* __restrict__ x4frag, f16* __restrict__ zfrag) {
  __shared__ float lds[2664];
  f16* bf = (f16*)lds;                  // 4 k-tiles x 512 f16 (x4-new B-frags)
  f16* zt = (f16*)(lds + 1024);         // 128 x 24 f16 (Z tile)
  float* gmu = lds + 2600;
  float* grs = lds + 2632;
  const int t = threadIdx.x;
  const int lane = t & 63, w = t >> 6;
  if (t < 32) {
    float s = 0.f, ss = 0.f;
    #pragma unroll
    for (int o = 0; o < 4; ++o)
      #pragma unroll
      for (int qa = 0; qa < 4; ++qa) {
        s  += statp[((4 * t + o) * 4 + qa) * 2];
        ss += statp[((4 * t + o) * 4 + qa) * 2 + 1];
      }
    float mu = s * (1.f / 16384.f);
    float var = ss * (1.f / 16384.f) - mu * mu;
    gmu[t] = mu;
    grs[t] = rsqrtf(var + 1e-5f);
  }
  __syncthreads();
  const int nb = blockIdx.x * 16;
  const int n = nb + (t & 15);
  const int q16 = t >> 4;
  float res[8];
  #pragma unroll
  for (int gi = 0; gi < 2; ++gi) {
    const int g = 2 * q16 + gi;
    const float mu = gmu[g], rstd = grs[g];
    float cn[4], xo[4];
    float inner = 0.f;
    #pragma unroll
    for (int o = 0; o < 4; ++o) {
      const int chn = 4 * g + o;
      float cv = (cb[(size_t)chn * NN + n] - mu) * rstd * gng[chn] + gnb[chn];
      float xv = x4[(size_t)chn * NN + n];
      cn[o] = cv; xo[o] = xv; inner += cv * xv;
    }
    float ssq = 0.f, xn[4];
    #pragma unroll
    for (int o = 0; o < 4; ++o) {
      xn[o] = xo[o] + (cn[o] - inner * xo[o]);
      ssq += xn[o] * xn[o];
    }
    float inv = 1.f / (sqrtf(ssq) + 1e-6f);
    #pragma unroll
    for (int o = 0; o < 4; ++o) {
      float vv = xn[o] * inv;
      res[gi * 4 + o] = vv;
      x4[(size_t)(4 * g + o) * NN + n] = vv;
    }
  }
  {
    f16x8 fr;
    #pragma unroll
    for (int j = 0; j < 8; ++j) fr[j] = (f16)res[j];
    *(f16x8*)(bf + (q16 >> 2) * 512 + (((n & 15) + 16 * (q16 & 3)) << 3)) = fr;
  }
  __syncthreads();
  // x4 n-frags (always)
  {
    const int kt = t >> 6, s2 = t & 63;
    *(f16x8*)(x4frag + ((size_t)kt * 256 + (nb >> 4)) * 512 + s2 * 8)
        = *(const f16x8*)(bf + kt * 512 + s2 * 8);
  }
  if (!zfrag) return;
  // Z = Wc @ x4_new  (wave w: output rows 32w..32w+31)
  f32x4v za0 = (f32x4v){0,0,0,0}, za1 = (f32x4v){0,0,0,0};
  #pragma unroll
  for (int kt = 0; kt < 4; ++kt) {
    f16x8 a0 = *(const f16x8*)(wcfrag + ((size_t)(2 * w) * 4 + kt) * 512 + lane * 8);
    f16x8 a1 = *(const f16x8*)(wcfrag + ((size_t)(2 * w + 1) * 4 + kt) * 512 + lane * 8);
    f16x8 bv = *(const f16x8*)(bf + kt * 512 + lane * 8);
    za0 = __builtin_amdgcn_mfma_f32_16x16x32_f16(a0, bv, za0, 0, 0, 0);
    za1 = __builtin_amdgcn_mfma_f32_16x16x32_f16(a1, bv, za1, 0, 0, 0);
  }
  const int colz = lane & 15;
  const int rz = (lane >> 4) << 2;
  #pragma unroll
  for (int j = 0; j < 4; ++j) {
    zt[(w * 32 + rz + j) * 24 + colz]      = (f16)za0[j];
    zt[(w * 32 + 16 + rz + j) * 24 + colz] = (f16)za1[j];
  }
  __syncthreads();
  {
    // 256 threads: ch = t&127, node-octet = t>>7 (2 octets x 8 = all 16 nodes)
    const int ch = t & 127, noct = t >> 7;
    f16x8 fr = *(const f16x8*)(zt + ch * 24 + noct * 8);
    const int nn2 = nb + noct * 8;
    *(f16x8*)(zfrag + ((size_t)(nn2 >> 5) * 8 + (ch >> 4)) * 512
                    + (((ch & 15) + 16 * ((nn2 & 31) >> 3)) << 3)) = fr;
  }
}

// ---------------- fused readout tail: logits = (out_w @ ro_w2) @ mag + fused bias ----------
__global__ void head(const float* __restrict__ mag, const float* __restrict__ rw2,
                     const float* __restrict__ rb2, const float* __restrict__ ow,
                     const float* __restrict__ ob, float* __restrict__ out) {
  __shared__ float fw[4][32];
  __shared__ float fb[4];
  const int t = threadIdx.x;
  if (t < 128) {
    const int k = t >> 5, m = t & 31;
    float s = 0.f;
    for (int o = 0; o < 128; ++o) s += ow[k * 128 + o] * rw2[o * 32 + m];
    fw[k][m] = s;
  } else if (t < 132) {
    const int k = t - 128;
    float s = ob[k];
    for (int o = 0; o < 128; ++o) s += ow[k * 128 + o] * rb2[o];
    fb[k] = s;
  }
  __syncthreads();
  const int n = blockIdx.x * 256 + t;
  float a0 = fb[0], a1 = fb[1], a2 = fb[2], a3 = fb[3];
  for (int m = 0; m < 32; ++m) {
    float v = mag[(size_t)m * NN + n];
    a0 += fw[0][m] * v; a1 += fw[1][m] * v; a2 += fw[2][m] * v; a3 += fw[3][m] * v;
  }
  f4 r; r.x = a0; r.y = a1; r.z = a2; r.w = a3;
  ((f4*)out)[n] = r;
}

extern "C" void kernel_launch(void* const* d_in, const int* in_sizes, int n_in,
                              void* d_out, int out_size, void* d_ws, size_t ws_size,
                              hipStream_t stream) {
  const float* x      = (const float*)d_in[0];
  const float* adj    = (const float*)d_in[1];
  const float* mc_w0  = (const float*)d_in[2];
  const float* mc_b0  = (const float*)d_in[3];
  const float* mc_w1  = (const float*)d_in[4];
  const float* mc_b1  = (const float*)d_in[5];
  const float* mc_w2  = (const float*)d_in[6];
  const float* mc_b2  = (const float*)d_in[7];
  const float* mc_w3  = (const float*)d_in[8];
  const float* mc_b3  = (const float*)d_in[9];
  const float* proj_w = (const float*)d_in[10];
  const float* proj_b = (const float*)d_in[11];
  const float* pat_w  = (const float*)d_in[12];
  const float* pat_b  = (const float*)d_in[13];
  const float* kur_wc = (const float*)d_in[14];
  const float* kur_bc = (const float*)d_in[15];
  const float* kur_wy = (const float*)d_in[16];
  const float* kur_by = (const float*)d_in[17];
  const float* gn_g   = (const float*)d_in[18];
  const float* gn_b   = (const float*)d_in[19];
  const float* ro_w1  = (const float*)d_in[20];
  const float* ro_b1  = (const float*)d_in[21];
  const float* ro_w2  = (const float*)d_in[22];
  const float* ro_b2  = (const float*)d_in[23];
  const float* out_w  = (const float*)d_in[24];
  const float* out_b  = (const float*)d_in[25];
  float* out = (float*)d_out;
  float* Wf = (float*)d_ws;

  // ---- workspace layout (float-word offsets), ~67.4 MB ----
  f16*   adj16    = (f16*)d_ws;                  // 32 MB
  float* part     = Wf + 8388608;                // 8 MB (csp alias)
  float* csp      = part;
  f16*   fragN    = (f16*)(Wf + 10485760);       // 3.5 MB (im2col, then gst frags)
  f16*   fragA    = (f16*)(Wf + 11403264);       // 0.5 MB
  f16*   fragB    = (f16*)(Wf + 11534336);       // 1 MB
  float* xT       = Wf + 11796480;               // 1 MB
  float* A1       = Wf + 12058624;               // 1 MB
  float* A2       = Wf + 12320768;               // 1 MB (magb alias)
  float* s1cat    = Wf + 12582912;               // 2 MB
  float* B1       = Wf + 13107200;               // 2 MB (wpart/Weff alias, early)
  float* wpart    = B1;
  float* Weff     = Wf + 13238272;
  float* B2       = Wf + 13631488;               // 2 MB
  float* gstf     = Wf + 14155776;               // 7 MB; alias after gst2frag:
  float* cbuf     = gstf;                        //   2 MB
  float* x4       = Wf + 14680064;               // 2 MB
  f16*   x4frag   = (f16*)(Wf + 15204352);       // 1 MB
  float* cy       = Wf + 15990784;               // 2 MB
  f16*   zfrag    = (f16*)(Wf + 16515072);       // 1 MB
  f16*   wcyfrag  = (f16*)(Wf + 16777216);       // 112 KB
  f16*   patfrag  = (f16*)(Wf + 16805888);       // 112 KB
  f16*   wcfrag   = (f16*)(Wf + 16834560);       // 32 KB
  f16*   row1frag = (f16*)(Wf + 16842752);       // 32 KB
  float* deg      = Wf + 16850944;               // 16 KB
  float* beff     = Wf + 16855040;               // 128
  float* cyb      = Wf + 16855168;               // 128
  float* statp    = Wf + 16855296;               // 4 KB (128 ch x 4 quarters x 2)
  float* magb     = A2;

  dim3 b256(256);

  // 1. adj -> fp16 A-frags + degree
  convert_cs2<<<dim3(128, 8), b256, 0, stream>>>(adj, adj16, csp);
  colsum_fin<<<dim3(16), b256, 0, stream>>>(csp, deg);

  // 2. weight folds
  wfold1<<<dim3(16), b256, 0, stream>>>(proj_w, mc_w0, mc_w1, mc_w2, mc_w3, wpart);
  wfold_asm<<<dim3(32), b256, 0, stream>>>(wpart, proj_w, proj_b,
                                           mc_b0, mc_b1, mc_b2, mc_b3, Weff, beff);
  wfold2<<<dim3(14), b256, 0, stream>>>(kur_wy, Weff, beff, kur_by, kur_bc, wcyfrag, cyb);
  wprep<<<dim3(352), b256, 0, stream>>>(pat_w, kur_wc, ro_w1, patfrag, wcfrag, row1frag);

  // 3. x transpose + frags; im2col; cy = conv(x, Wcy) + cyb
  transpose_x<<<dim3(64), b256, 0, stream>>>(x, deg, xT, gstf, fragA);
  im2col<<<dim3(896), b256, 0, stream>>>(x, fragN);
  wgemm<14, 0><<<dim3(128), b256, 0, stream>>>(wcyfrag, fragN, cyb, cy, nullptr);

  // 4. GST first order (F=64, KZ=8; 2048-block adjmm, 256-block reduce)
  adjmm16<64, 8><<<dim3(2048), b256, 0, stream>>>(adj16, fragA, part);
  reduce_P<<<dim3(256), b256, 0, stream>>>(part, xT, xT, A1, fragA, 4,
                                           fragB, 0, gstf, 1, 1, s1cat, deg, 64, 8);
  adjmm16<64, 8><<<dim3(2048), b256, 0, stream>>>(adj16, fragA, part);
  reduce_P<<<dim3(256), b256, 0, stream>>>(part, A1, A1, A2, fragA, 4,
                                           fragB, 64, gstf, 2, 2, s1cat + (size_t)64 * NN, deg, 64, 8);
  adjmm16<64, 8><<<dim3(2048), b256, 0, stream>>>(adj16, fragA, part);
  reduce_P<<<dim3(256), b256, 0, stream>>>(part, A2, nullptr, A1, fragA, 4,
                                           nullptr, 0, nullptr, -1, -1, nullptr, deg, 64, 8);
  adjmm16<64, 8><<<dim3(2048), b256, 0, stream>>>(adj16, fragA, part);
  reduce_P<<<dim3(256), b256, 0, stream>>>(part, A1, A2, A1, nullptr, 4,
                                           nullptr, 0, gstf, 3, 3, nullptr, deg, 64, 8);

  // 5. GST second order (F=128, KZ=4; 1024-block adjmm, 512-block reduce)
  adjmm16<128, 4><<<dim3(1024), b256, 0, stream>>>(adj16, fragB, part);
  reduce_P<<<dim3(512), b256, 0, stream>>>(part, s1cat, nullptr, B1, fragB, 8,
                                           nullptr, 0, nullptr, -1, -1, nullptr, deg, 128, 4);
  adjmm16<128, 4><<<dim3(1024), b256, 0, stream>>>(adj16, fragB, part);
  reduce_P<<<dim3(512), b256, 0, stream>>>(part, B1, B1, B2, fragB, 8,
                                           nullptr, 0, gstf, 4, -1, nullptr, deg, 128, 4);
  adjmm16<128, 4><<<dim3(1024), b256, 0, stream>>>(adj16, fragB, part);
  reduce_P<<<dim3(512), b256, 0, stream>>>(part, B2, nullptr, B1, fragB, 8,
                                           nullptr, 0, nullptr, -1, -1, nullptr, deg, 128, 4);
  adjmm16<128, 4><<<dim3(1024), b256, 0, stream>>>(adj16, fragB, part);
  reduce_P<<<dim3(512), b256, 0, stream>>>(part, B1, B2, B1, nullptr, 8,
                                           nullptr, 0, gstf, 5, 6, nullptr, deg, 128, 4);

  // 6. gst -> n-frags; x0 GEMM + osc-norm; Z0
  gst2frag<<<dim3(64, 7), b256, 0, stream>>>(gstf, fragN);
  wgemm<14, 1><<<dim3(128), b256, 0, stream>>>(patfrag, fragN, pat_b, x4, x4frag);
  wgemm<4, 2><<<dim3(128), b256, 0, stream>>>(wcfrag, x4frag, nullptr, nullptr, zfrag);

  // 7. Kuramoto dynamics: 3 kernels/iter; last iter skips Z emission
  for (int q = 0; q < 8; ++q) {
    adjmm16<128, 4><<<dim3(1024), b256, 0, stream>>>(adj16, zfrag, part);
    reduce_stats<<<dim3(512), b256, 0, stream>>>(part, cy, cbuf, statp);
    kur_fin<<<dim3(256), b256, 0, stream>>>(cbuf, statp, gn_g, gn_b, wcfrag,
                                            x4, x4frag, (q < 7) ? zfrag : nullptr);
  }

  // 8. readout magnitude + fused head
  wgemm<4, 3><<<dim3(128), b256, 0, stream>>>(row1frag, x4frag, ro_b1, magb, nullptr);
  head<<<dim3(16), b256, 0, stream>>>(magb, ro_w2, ro_b2, out_w, out_b, out);
}

// Round 13
// 466.438 us; speedup vs baseline: 1.2322x; 1.0002x over previous
//
#include <hip/hip_runtime.h>
#include <math.h>

#define NN 4096

typedef float4 f4;
typedef _Float16 f16;
typedef _Float16 f16x8 __attribute__((ext_vector_type(8)));
typedef _Float16 h4 __attribute__((ext_vector_type(4)));
typedef float f32x4v __attribute__((ext_vector_type(4)));

// adjmm-convention B-frag offset (f16 units): ch = output column, n = reduction (node)
__device__ __forceinline__ size_t frag_off(int CT, int ch, int n) {
  return ((size_t)(n >> 5) * CT + (ch >> 4)) * 512
       + (size_t)((((ch & 15) + (((n & 31) >> 3) << 4)) << 3) + (n & 7));
}
// n-convention B-frag (for wgemm): col = node n (4096 wide -> CT=256), k = feature
__device__ __forceinline__ size_t nfrag_off(int k, int n) {
  return ((size_t)(k >> 5) * 256 + (n >> 4)) * 512
       + (size_t)((((n & 15) + (((k & 31) >> 3) << 4)) << 3) + (k & 7));
}
// A-frag offset (weights, M=128): row o, reduction k
__device__ __forceinline__ size_t afrag_off(int K32, int o, int k) {
  return ((size_t)(o >> 4) * K32 + (k >> 5)) * 512
       + (size_t)((((o & 15) + (((k & 31) >> 3) << 4)) << 3) + (k & 7));
}

// ---------------- adj fp32 -> fp16 A-frags (LDS-staged, coalesced) + colsum partials -------
__global__ __launch_bounds__(256)
void convert_cs2(const float* __restrict__ adj, f16* __restrict__ adj16,
                 float* __restrict__ csp) {
  __shared__ f16 lds16[32][520];
  const int rb = blockIdx.x;        // 128 blocks of 32 rows
  const int cb = blockIdx.y;        // 8 col blocks of 512
  const int t = threadIdx.x;
  const int half = t >> 7;          // 2 row halves of 16
  const int u = t & 127;
  const int c0 = cb * 512 + u * 4;
  float cs0 = 0.f, cs1 = 0.f, cs2 = 0.f, cs3 = 0.f;
  #pragma unroll 4
  for (int r = 0; r < 16; ++r) {
    const int i = rb * 32 + half * 16 + r;
    f4 v = *(const f4*)(adj + (size_t)i * NN + c0);
    cs0 += v.x; cs1 += v.y; cs2 += v.z; cs3 += v.w;
    h4 hv; hv[0] = (f16)v.x; hv[1] = (f16)v.y; hv[2] = (f16)v.z; hv[3] = (f16)v.w;
    *(h4*)&lds16[half * 16 + r][u * 4] = hv;
  }
  f4 cv; cv.x = cs0; cv.y = cs1; cv.z = cs2; cv.w = cs3;
  *(f4*)(csp + (size_t)(rb * 2 + half) * NN + c0) = cv;
  __syncthreads();
  const int rt = rb * 2 + half;
  f16* dst = adj16 + ((size_t)rt * 128 + cb * 16) * 512;
  #pragma unroll
  for (int s = 0; s < 8; ++s) {
    const int e = s * 1024 + u * 8;
    const int bl = e >> 9;
    const int l = (e >> 3) & 63;
    const int row = half * 16 + (l & 15);
    const int col = bl * 32 + (l >> 4) * 8;
    f16x8 fr = *(const f16x8*)&lds16[row][col];
    *(f16x8*)(dst + e) = fr;
  }
}

__global__ void colsum_fin(const float* __restrict__ csp, float* __restrict__ deg_inv) {
  int j = blockIdx.x * 256 + threadIdx.x;
  float s = 0.f;
  for (int rb = 0; rb < 256; ++rb) s += csp[(size_t)rb * NN + j];
  deg_inv[j] = 1.0f / (s + 1e-6f);
}

// ---------------- weight fold 1: per (branch, tap) GEMM into wpart ----------------
__global__ __launch_bounds__(256)
void wfold1(const float* __restrict__ proj_w,
            const float* __restrict__ w0, const float* __restrict__ w1,
            const float* __restrict__ w2, const float* __restrict__ w3,
            float* __restrict__ wpart) {
  __shared__ float projs[128][65];
  __shared__ float wk[64][65];
  const int b = blockIdx.x;
  int br, kp;
  if (b == 0) { br = 0; kp = 0; }
  else if (b < 4) { br = 1; kp = b - 1; }
  else if (b < 9) { br = 2; kp = b - 4; }
  else { br = 3; kp = b - 9; }
  const int Kbr = 2 * br + 1;
  const float* Wbr = (br == 0) ? w0 : (br == 1) ? w1 : (br == 2) ? w2 : w3;
  const int baseo[4] = {0, 8192, 32768, 73728};
  const int t = threadIdx.x;
  #pragma unroll
  for (int r = 0; r < 32; ++r) {
    int e = r * 256 + t; int o = e >> 6, cp = e & 63;
    projs[o][cp] = proj_w[(size_t)o * 256 + br * 64 + cp];
  }
  #pragma unroll
  for (int r = 0; r < 16; ++r) {
    int e = r * 256 + t; int cp = e >> 6, c = e & 63;
    wk[cp][c] = Wbr[(size_t)(cp * 64 + c) * Kbr + kp];
  }
  __syncthreads();
  for (int i = 0; i < 32; ++i) {
    int e = i * 256 + t; int o = e >> 6, c = e & 63;
    float s = 0.f;
    #pragma unroll 8
    for (int cp = 0; cp < 64; ++cp) s += projs[o][cp] * wk[cp][c];
    wpart[baseo[br] + (size_t)(o * 64 + c) * Kbr + kp] = s;
  }
}

// ---------------- weight fold assemble: Weff[o][c][7] + beff ----------------
__global__ void wfold_asm(const float* __restrict__ wpart, const float* __restrict__ proj_w,
                          const float* __restrict__ proj_b,
                          const float* __restrict__ b0, const float* __restrict__ b1,
                          const float* __restrict__ b2, const float* __restrict__ b3,
                          float* __restrict__ Weff, float* __restrict__ beff) {
  const int id = blockIdx.x * 256 + threadIdx.x;
  const int o = id >> 6, c = id & 63;
  const int oc = o * 64 + c;
  #pragma unroll
  for (int k = 0; k < 7; ++k) {
    float s = 0.f;
    if (k == 3)            s += wpart[oc];
    if (k >= 2 && k <= 4)  s += wpart[8192  + oc * 3 + (k - 2)];
    if (k >= 1 && k <= 5)  s += wpart[32768 + oc * 5 + (k - 1)];
    s += wpart[73728 + oc * 7 + k];
    Weff[(size_t)oc * 7 + k] = s;
  }
  if (blockIdx.x == 0 && threadIdx.x < 128) {
    const int oo = threadIdx.x;
    float s = proj_b[oo];
    for (int j = 0; j < 64; ++j) {
      s += proj_w[(size_t)oo * 256 + j] * b0[j];
      s += proj_w[(size_t)oo * 256 + 64 + j] * b1[j];
      s += proj_w[(size_t)oo * 256 + 128 + j] * b2[j];
      s += proj_w[(size_t)oo * 256 + 192 + j] * b3[j];
    }
    beff[oo] = s;
  }
}

// ---------------- weight fold 2: Wcy = kur_wy @ Weff -> f16 A-frags; cyb ----------------
__global__ __launch_bounds__(256)
void wfold2(const float* __restrict__ kur_wy, const float* __restrict__ Weff,
            const float* __restrict__ beff, const float* __restrict__ kur_by,
            const float* __restrict__ kur_bc,
            f16* __restrict__ wcyfrag, float* __restrict__ cyb) {
  __shared__ float wyh[128][65];
  __shared__ float weffL[128][33];
  const int ckb = blockIdx.x * 32;
  const int t = threadIdx.x;
  const int o = t & 127, hh = t >> 7;
  #pragma unroll
  for (int r = 0; r < 16; ++r) {
    int e = r * 256 + t; int op = e >> 5, ck = e & 31;
    weffL[op][ck] = Weff[(size_t)op * 448 + ckb + ck];
  }
  float acc[16];
  #pragma unroll
  for (int i = 0; i < 16; ++i) acc[i] = 0.f;
  float bacc = 0.f;
  for (int h = 0; h < 2; ++h) {
    __syncthreads();
    #pragma unroll
    for (int r = 0; r < 32; ++r) {
      int e = r * 256 + t; int oo = e >> 6, o2 = e & 63;
      wyh[oo][o2] = kur_wy[(size_t)oo * 128 + h * 64 + o2];
    }
    __syncthreads();
    for (int oo = 0; oo < 64; ++oo) {
      float w = wyh[o][oo];
      int op = h * 64 + oo;
      #pragma unroll
      for (int i = 0; i < 16; ++i) acc[i] += w * weffL[op][hh * 16 + i];
      if (t < 128) bacc += w * beff[op];
    }
  }
  #pragma unroll
  for (int i = 0; i < 16; ++i) {
    int ck = ckb + hh * 16 + i;
    int c = ck / 7, kt = ck % 7;
    wcyfrag[afrag_off(14, o, kt * 64 + c)] = (f16)acc[i];
  }
  if (blockIdx.x == 0 && t < 128) cyb[t] = bacc + kur_by[t] + kur_bc[t];
}

// ---------------- convert pat_w / kur_wc / ro_w1 to f16 A-frags + head weight fold --------
__global__ void wprep(const float* __restrict__ pat_w, const float* __restrict__ kur_wc,
                      const float* __restrict__ ro_w1,
                      const float* __restrict__ rw2, const float* __restrict__ rb2,
                      const float* __restrict__ ow, const float* __restrict__ ob,
                      f16* __restrict__ patfrag, f16* __restrict__ wcfrag,
                      f16* __restrict__ row1frag, float* __restrict__ hw) {
  const int id = blockIdx.x * 256 + threadIdx.x;
  if (id < 57344) {
    int o = id / 448, k = id % 448;
    patfrag[afrag_off(14, o, k)] = (f16)pat_w[id];
  } else if (id < 73728) {
    int e = id - 57344; int o = e >> 7, k = e & 127;
    wcfrag[afrag_off(4, o, k)] = (f16)kur_wc[e];
  } else if (id < 90112) {
    int e = id - 73728; int o = e >> 7, k = e & 127;
    row1frag[afrag_off(4, o, k)] = (f16)ro_w1[e];
  } else {
    // head fold: hw[0..127] = (out_w @ ro_w2)[k][m], hw[128..131] = out_b + out_w@rb2
    int e = id - 90112;
    if (e < 128) {
      const int k = e >> 5, m = e & 31;
      float s = 0.f;
      for (int o = 0; o < 128; ++o) s += ow[k * 128 + o] * rw2[o * 32 + m];
      hw[e] = s;
    } else if (e < 132) {
      const int k = e - 128;
      float s = ob[k];
      for (int o = 0; o < 128; ++o) s += ow[k * 128 + o] * rb2[o];
      hw[128 + k] = s;
    }
  }
}

// ---------------- x[N,64] -> xT[64][N] + gst coef0 row + fragA (x*deg_inv) ----------------
__global__ void transpose_x(const float* __restrict__ x, const float* __restrict__ deg,
                            float* __restrict__ xT, float* __restrict__ gst,
                            f16* __restrict__ fragA) {
  __shared__ float T[64][65];
  const int nb = blockIdx.x * 64;
  const int t = threadIdx.x;
  #pragma unroll
  for (int r = 0; r < 16; ++r) {
    int e = r * 256 + t; int nl = e >> 6, f = e & 63;
    T[nl][f] = x[(size_t)(nb + nl) * 64 + f];
  }
  __syncthreads();
  #pragma unroll
  for (int r = 0; r < 16; ++r) {
    int e = r * 256 + t; int f = e >> 6, nl = e & 63;
    float v = T[nl][f];
    xT[(size_t)f * NN + nb + nl] = v;
    gst[(size_t)f * 7 * NN + nb + nl] = v;
  }
  #pragma unroll
  for (int k = 0; k < 2; ++k) {
    int fi = k * 256 + t;
    int f = fi >> 3, n0l = (fi & 7) << 3;
    f16x8 fr;
    #pragma unroll
    for (int j = 0; j < 8; ++j) fr[j] = (f16)(T[n0l + j][f] * deg[nb + n0l + j]);
    *(f16x8*)(fragA + frag_off(4, f, nb + n0l)) = fr;
  }
}

// ---------------- im2col: x -> n-frags [k = dk*64+c][n], zero-padded ----------------
__global__ void im2col(const float* __restrict__ x, f16* __restrict__ fragN) {
  const int ot = blockIdx.x * 256 + threadIdx.x;
  const int q = ot >> 12;
  const int n = ot & 4095;
  const int dk = q >> 3;
  const int c0 = (q & 7) * 8;
  const int np = n + dk - 3;
  f16x8 fr;
  if (np >= 0 && np < NN) {
    const float* src = x + (size_t)np * 64 + c0;
    f4 v0 = *(const f4*)src, v1 = *(const f4*)(src + 4);
    fr[0]=(f16)v0.x; fr[1]=(f16)v0.y; fr[2]=(f16)v0.z; fr[3]=(f16)v0.w;
    fr[4]=(f16)v1.x; fr[5]=(f16)v1.y; fr[6]=(f16)v1.z; fr[7]=(f16)v1.w;
  } else {
    #pragma unroll
    for (int j = 0; j < 8; ++j) fr[j] = (f16)0.f;
  }
  *(f16x8*)(fragN + nfrag_off(q * 8, n)) = fr;
}

// ---------------- MFMA split-K GEMM vs adjacency, v3: 16-row tiles, 2-step LDS reduce -----
// block b: rows (b&255)*16..+16, K-chunk kz = b>>8; 4 waves split the block's K-range.
// UNROLL: 4 for F=64 (low VGPR), 2 for F=128 (avoid occupancy cliff).
template<int F, int KZ>
__global__ __launch_bounds__(256)
void adjmm16(const f16* __restrict__ adj16, const f16* __restrict__ rhs,
             float* __restrict__ part) {
  constexpr int CT = F / 16;
  constexpr int KSB = (NN / KZ) / 32;   // K-steps per block
  constexpr int KS = KSB / 4;           // K-steps per wave
  const int t = threadIdx.x;
  const int lane = t & 63, w = t >> 6;
  const int mt = blockIdx.x & 255;      // 16-row tile
  const int kz = blockIdx.x >> 8;
  const int kt0 = kz * KSB + w * KS;
  const size_t aoff = ((size_t)mt * 128 + kt0) * 512 + (size_t)lane * 8;
  const f16* bb = rhs + (size_t)kt0 * CT * 512 + lane * 8;
  f32x4v acc[CT];
  #pragma unroll
  for (int c = 0; c < CT; ++c) acc[c] = (f32x4v){0.f, 0.f, 0.f, 0.f};
  if constexpr (CT == 4) {
    #pragma unroll 4
    for (int i = 0; i < KS; ++i) {
      f16x8 a = *(const f16x8*)(adj16 + aoff + (size_t)i * 512);
      #pragma unroll
      for (int c = 0; c < CT; ++c) {
        f16x8 bv = *(const f16x8*)(bb + ((size_t)i * CT + c) * 512);
        acc[c] = __builtin_amdgcn_mfma_f32_16x16x32_f16(a, bv, acc[c], 0, 0, 0);
      }
    }
  } else {
    #pragma unroll 2
    for (int i = 0; i < KS; ++i) {
      f16x8 a = *(const f16x8*)(adj16 + aoff + (size_t)i * 512);
      #pragma unroll
      for (int c = 0; c < CT; ++c) {
        f16x8 bv = *(const f16x8*)(bb + ((size_t)i * CT + c) * 512);
        acc[c] = __builtin_amdgcn_mfma_f32_16x16x32_f16(a, bv, acc[c], 0, 0, 0);
      }
    }
  }
  __shared__ float redf[2 * CT * 256];
  // step 1: waves 2,3 store
  if (w >= 2) {
    float* myw = redf + (w - 2) * (CT * 256);
    #pragma unroll
    for (int c = 0; c < CT; ++c) *(f32x4v*)(myw + c * 256 + lane * 4) = acc[c];
  }
  __syncthreads();
  // step 2: waves 0,1 add partner (w+2) and store
  if (w < 2) {
    float* myw = redf + w * (CT * 256);
    #pragma unroll
    for (int c = 0; c < CT; ++c) {
      acc[c] += *(const f32x4v*)(myw + c * 256 + lane * 4);
      *(f32x4v*)(myw + c * 256 + lane * 4) = acc[c];
    }
  }
  __syncthreads();
  float* pb = part + (size_t)kz * F * NN;
  constexpr int SLOTS = CT * 64;        // f4 slots (16 nodes x F ch / 4)
  #pragma unroll
  for (int s = 0; s < SLOTS; s += 256) {
    const int slot = s + t;
    f32x4v v = *(const f32x4v*)(redf + slot * 4);
    v += *(const f32x4v*)(redf + CT * 256 + slot * 4);
    const int ct = slot >> 6, l = slot & 63;
    const int ch = ct * 16 + (l & 15);
    const int node0 = mt * 16 + ((l >> 4) << 2);
    *(f32x4v*)(pb + (size_t)ch * NN + node0) = v;
  }
}

// ---------------- reduce split-K + P epilogue + frag/diff/gst/s1 fusion (f4/thread) -------
__global__ void reduce_P(const float* __restrict__ part, const float* __restrict__ u,
                         const float* __restrict__ D, float* __restrict__ outp,
                         f16* __restrict__ fragNext, int nextCT,
                         f16* __restrict__ fragDiff, int diffChOff,
                         float* __restrict__ gstf, int coefLo, int coefHi,
                         float* __restrict__ s1buf, const float* __restrict__ deg,
                         int F, int KZ) {
  const int id = blockIdx.x * 256 + threadIdx.x;
  const int ch = id >> 10, n0 = (id & 1023) << 2;
  const size_t base = (size_t)ch * NN + n0;
  float a0 = 0.f, a1 = 0.f, a2 = 0.f, a3 = 0.f;
  for (int z = 0; z < KZ; ++z) {
    f4 p = *(const f4*)(part + (size_t)z * F * NN + base);
    a0 += p.x; a1 += p.y; a2 += p.z; a3 += p.w;
  }
  f4 u0 = *(const f4*)(u + base);
  float o0 = 0.5f * (u0.x + a0), o1 = 0.5f * (u0.y + a1);
  float o2 = 0.5f * (u0.z + a2), o3 = 0.5f * (u0.w + a3);
  f4 ov; ov.x = o0; ov.y = o1; ov.z = o2; ov.w = o3;
  *(f4*)(outp + base) = ov;
  if (fragNext) {
    f4 dg = *(const f4*)(deg + n0);
    h4 fr;
    fr[0] = (f16)(o0 * dg.x); fr[1] = (f16)(o1 * dg.y);
    fr[2] = (f16)(o2 * dg.z); fr[3] = (f16)(o3 * dg.w);
    *(h4*)(fragNext + frag_off(nextCT, ch, n0)) = fr;
  }
  if (D) {
    f4 d0 = *(const f4*)(D + base);
    float e0 = fabsf(d0.x - o0), e1 = fabsf(d0.y - o1);
    float e2 = fabsf(d0.z - o2), e3 = fabsf(d0.w - o3);
    f4 ev; ev.x = e0; ev.y = e1; ev.z = e2; ev.w = e3;
    if (s1buf) *(f4*)(s1buf + base) = ev;
    if (fragDiff) {
      f4 dg = *(const f4*)(deg + n0);
      h4 fr;
      fr[0] = (f16)(e0 * dg.x); fr[1] = (f16)(e1 * dg.y);
      fr[2] = (f16)(e2 * dg.z); fr[3] = (f16)(e3 * dg.w);
      *(h4*)(fragDiff + frag_off(8, diffChOff + ch, n0)) = fr;
    }
    if (gstf) {
      int coef = (ch < 64) ? coefLo : coefHi;
      if (coef >= 0)
        *(f4*)(gstf + (size_t)((ch & 63) * 7 + coef) * NN + n0) = ev;
    }
  }
}

// ---------------- gstf fp32 rows -> n-frags (LDS transpose) ----------------
__global__ void gst2frag(const float* __restrict__ gstf, f16* __restrict__ fragN) {
  __shared__ float T[64][65];
  const int nb = blockIdx.x * 64;
  const int kb = blockIdx.y * 64;
  const int t = threadIdx.x;
  #pragma unroll
  for (int r = 0; r < 16; ++r) {
    int e = r * 256 + t; int row = e >> 6, col = e & 63;
    T[row][col] = gstf[(size_t)(kb + row) * NN + nb + col];
  }
  __syncthreads();
  #pragma unroll
  for (int h = 0; h < 2; ++h) {
    int idx = h * 256 + t;
    int q = idx >> 6, n = idx & 63;
    f16x8 fr;
    #pragma unroll
    for (int j = 0; j < 8; ++j) fr[j] = (f16)T[q * 8 + j][n];
    *(f16x8*)(fragN + nfrag_off(kb + q * 8, nb + n)) = fr;
  }
}

// ---------------- generic MFMA wgemm (EPI 0/1/2/3 as before) ----------------
template<int K32, int EPI>
__global__ __launch_bounds__(256)
void wgemm(const f16* __restrict__ A, const f16* __restrict__ B,
           const float* __restrict__ bias, float* __restrict__ out,
           f16* __restrict__ ofrag) {
  const int t = threadIdx.x;
  const int lane = t & 63, w = t >> 6;
  const int nb = blockIdx.x * 32;
  const size_t a0b = ((size_t)(2 * w) * K32) * 512 + lane * 8;
  const size_t a1b = ((size_t)(2 * w + 1) * K32) * 512 + lane * 8;
  const size_t b0b = (size_t)(nb >> 4) * 512 + lane * 8;
  f32x4v acc[2][2];
  acc[0][0] = (f32x4v){0,0,0,0}; acc[0][1] = (f32x4v){0,0,0,0};
  acc[1][0] = (f32x4v){0,0,0,0}; acc[1][1] = (f32x4v){0,0,0,0};
  #pragma unroll
  for (int i = 0; i < K32; ++i) {
    f16x8 a0 = *(const f16x8*)(A + a0b + (size_t)i * 512);
    f16x8 a1 = *(const f16x8*)(A + a1b + (size_t)i * 512);
    f16x8 b0 = *(const f16x8*)(B + b0b + (size_t)i * 256 * 512);
    f16x8 b1 = *(const f16x8*)(B + b0b + (size_t)i * 256 * 512 + 512);
    acc[0][0] = __builtin_amdgcn_mfma_f32_16x16x32_f16(a0, b0, acc[0][0], 0, 0, 0);
    acc[0][1] = __builtin_amdgcn_mfma_f32_16x16x32_f16(a0, b1, acc[0][1], 0, 0, 0);
    acc[1][0] = __builtin_amdgcn_mfma_f32_16x16x32_f16(a1, b0, acc[1][0], 0, 0, 0);
    acc[1][1] = __builtin_amdgcn_mfma_f32_16x16x32_f16(a1, b1, acc[1][1], 0, 0, 0);
  }
  if constexpr (EPI == 0) {
    #pragma unroll
    for (int r = 0; r < 2; ++r)
      #pragma unroll
      for (int c = 0; c < 2; ++c) {
        int rowb = w * 32 + r * 16 + ((lane >> 4) << 2);
        int n = nb + c * 16 + (lane & 15);
        #pragma unroll
        for (int j = 0; j < 4; ++j)
          out[(size_t)(rowb + j) * NN + n] = acc[r][c][j] + bias[rowb + j];
      }
  } else if constexpr (EPI == 3) {
    #pragma unroll
    for (int r = 0; r < 2; ++r)
      #pragma unroll
      for (int c = 0; c < 2; ++c) {
        int rowb = w * 32 + r * 16 + ((lane >> 4) << 2);
        int n = nb + c * 16 + (lane & 15);
        float ss = 1e-6f;
        #pragma unroll
        for (int j = 0; j < 4; ++j) {
          float v = acc[r][c][j] + bias[rowb + j];
          ss += v * v;
        }
        out[(size_t)(rowb >> 2) * NN + n] = sqrtf(ss);
      }
  } else {
    __shared__ float tile[128][33];
    #pragma unroll
    for (int r = 0; r < 2; ++r)
      #pragma unroll
      for (int c = 0; c < 2; ++c) {
        int rowb = w * 32 + r * 16 + ((lane >> 4) << 2);
        int col = c * 16 + (lane & 15);
        #pragma unroll
        for (int j = 0; j < 4; ++j) tile[rowb + j][col] = acc[r][c][j];
      }
    __syncthreads();
    if constexpr (EPI == 1) {
      #pragma unroll
      for (int h = 0; h < 2; ++h) {
        int nl = (t & 15) + h * 16;
        int q = t >> 4;
        float v[8];
        #pragma unroll
        for (int j = 0; j < 8; ++j) v[j] = tile[q * 8 + j][nl] + bias[q * 8 + j];
        #pragma unroll
        for (int half = 0; half < 2; ++half) {
          float ss = 0.f;
          #pragma unroll
          for (int j = 0; j < 4; ++j) { float z = v[half * 4 + j]; ss += z * z; }
          float inv = 1.f / (sqrtf(ss) + 1e-6f);
          #pragma unroll
          for (int j = 0; j < 4; ++j) v[half * 4 + j] *= inv;
        }
        f16x8 fr;
        #pragma unroll
        for (int j = 0; j < 8; ++j) {
          out[(size_t)(q * 8 + j) * NN + nb + nl] = v[j];
          fr[j] = (f16)v[j];
        }
        *(f16x8*)(ofrag + nfrag_off(q * 8, nb + nl)) = fr;
      }
    } else {  // EPI == 2: Z adj-frags
      #pragma unroll
      for (int h = 0; h < 2; ++h) {
        int o = t & 127;
        int noct = (t >> 7) + h * 2;
        f16x8 fr;
        #pragma unroll
        for (int j = 0; j < 8; ++j) fr[j] = (f16)tile[o][noct * 8 + j];
        *(f16x8*)(ofrag + frag_off(8, o, nb + noct * 8)) = fr;
      }
    }
  }
}

// ---------------- reduce split-K + cy -> c ; per-(ch,quarter) stats partials -------------
__global__ __launch_bounds__(256)
void reduce_stats(const float* __restrict__ part, const float* __restrict__ cy,
                  float* __restrict__ c, float* __restrict__ statp) {
  const int b = blockIdx.x;
  const int ch = b >> 2, qa = b & 3;
  const int t = threadIdx.x;
  const int lane = t & 63, w = t >> 6;
  const size_t idx = (size_t)ch * 1024 + qa * 256 + t;   // f4 units
  f4 v = ((const f4*)cy)[idx];
  #pragma unroll
  for (int z = 0; z < 4; ++z) {
    f4 p = ((const f4*)part)[(size_t)z * 131072 + idx];
    v.x += p.x; v.y += p.y; v.z += p.z; v.w += p.w;
  }
  ((f4*)c)[idx] = v;
  float s  = v.x + v.y + v.z + v.w;
  float ss = v.x*v.x + v.y*v.y + v.z*v.z + v.w*v.w;
  #pragma unroll
  for (int off = 32; off > 0; off >>= 1) { s += __shfl_down(s, off); ss += __shfl_down(ss, off); }
  __shared__ float rs[4], rss[4];
  if (lane == 0) { rs[w] = s; rss[w] = ss; }
  __syncthreads();
  if (t == 0) {
    statp[(ch * 4 + qa) * 2]     = rs[0] + rs[1] + rs[2] + rs[3];
    statp[(ch * 4 + qa) * 2 + 1] = rss[0] + rss[1] + rss[2] + rss[3];
  }
}

// ---------------- fused: GN stats fin + Kuramoto update + Z = Wc @ x4_new (per-block) ------
// zfrag == nullptr: last iteration -> skip Z computation AND dead x4 fp32 store.
__global__ __launch_bounds__(256)
void kur_fin(const float* __restrict__ cb, const float* __restrict__ statp,
             const float* __restrict__ gng, const float* __restrict__ gnb,
             const f16* __restrict__ wcfrag, float* __restrict__ x4,
             f16* __restrict__ x4frag, f16* __restrict__ zfrag) {
  __shared__ float lds[2664];
  f16* bf = (f16*)lds;                  // 4 k-tiles x 512 f16 (x4-new B-frags)
  f16* zt = (f16*)(lds + 1024);         // 128 x 24 f16 (Z tile)
  float* gmu = lds + 2600;
  float* grs = lds + 2632;
  const int t = threadIdx.x;
  const int lane = t & 63, w = t >> 6;
  if (t < 32) {
    float s = 0.f, ss = 0.f;
    #pragma unroll
    for (int o = 0; o < 4; ++o)
      #pragma unroll
      for (int qa = 0; qa < 4; ++qa) {
        s  += statp[((4 * t + o) * 4 + qa) * 2];
        ss += statp[((4 * t + o) * 4 + qa) * 2 + 1];
      }
    float mu = s * (1.f / 16384.f);
    float var = ss * (1.f / 16384.f) - mu * mu;
    gmu[t] = mu;
    grs[t] = rsqrtf(var + 1e-5f);
  }
  __syncthreads();
  const int nb = blockIdx.x * 16;
  const int n = nb + (t & 15);
  const int q16 = t >> 4;
  float res[8];
  #pragma unroll
  for (int gi = 0; gi < 2; ++gi) {
    const int g = 2 * q16 + gi;
    const float mu = gmu[g], rstd = grs[g];
    float cn[4], xo[4];
    float inner = 0.f;
    #pragma unroll
    for (int o = 0; o < 4; ++o) {
      const int chn = 4 * g + o;
      float cv = (cb[(size_t)chn * NN + n] - mu) * rstd * gng[chn] + gnb[chn];
      float xv = x4[(size_t)chn * NN + n];
      cn[o] = cv; xo[o] = xv; inner += cv * xv;
    }
    float ssq = 0.f, xn[4];
    #pragma unroll
    for (int o = 0; o < 4; ++o) {
      xn[o] = xo[o] + (cn[o] - inner * xo[o]);
      ssq += xn[o] * xn[o];
    }
    float inv = 1.f / (sqrtf(ssq) + 1e-6f);
    #pragma unroll
    for (int o = 0; o < 4; ++o) {
      float vv = xn[o] * inv;
      res[gi * 4 + o] = vv;
      if (zfrag) x4[(size_t)(4 * g + o) * NN + n] = vv;  // dead on last iter
    }
  }
  {
    f16x8 fr;
    #pragma unroll
    for (int j = 0; j < 8; ++j) fr[j] = (f16)res[j];
    *(f16x8*)(bf + (q16 >> 2) * 512 + (((n & 15) + 16 * (q16 & 3)) << 3)) = fr;
  }
  __syncthreads();
  // x4 n-frags (always)
  {
    const int kt = t >> 6, s2 = t & 63;
    *(f16x8*)(x4frag + ((size_t)kt * 256 + (nb >> 4)) * 512 + s2 * 8)
        = *(const f16x8*)(bf + kt * 512 + s2 * 8);
  }
  if (!zfrag) return;
  // Z = Wc @ x4_new  (wave w: output rows 32w..32w+31)
  f32x4v za0 = (f32x4v){0,0,0,0}, za1 = (f32x4v){0,0,0,0};
  #pragma unroll
  for (int kt = 0; kt < 4; ++kt) {
    f16x8 a0 = *(const f16x8*)(wcfrag + ((size_t)(2 * w) * 4 + kt) * 512 + lane * 8);
    f16x8 a1 = *(const f16x8*)(wcfrag + ((size_t)(2 * w + 1) * 4 + kt) * 512 + lane * 8);
    f16x8 bv = *(const f16x8*)(bf + kt * 512 + lane * 8);
    za0 = __builtin_amdgcn_mfma_f32_16x16x32_f16(a0, bv, za0, 0, 0, 0);
    za1 = __builtin_amdgcn_mfma_f32_16x16x32_f16(a1, bv, za1, 0, 0, 0);
  }
  const int colz = lane & 15;
  const int rz = (lane >> 4) << 2;
  #pragma unroll
  for (int j = 0; j < 4; ++j) {
    zt[(w * 32 + rz + j) * 24 + colz]      = (f16)za0[j];
    zt[(w * 32 + 16 + rz + j) * 24 + colz] = (f16)za1[j];
  }
  __syncthreads();
  {
    const int ch = t & 127, noct = t >> 7;
    f16x8 fr = *(const f16x8*)(zt + ch * 24 + noct * 8);
    const int nn2 = nb + noct * 8;
    *(f16x8*)(zfrag + ((size_t)(nn2 >> 5) * 8 + (ch >> 4)) * 512
                    + (((ch & 15) + 16 * ((nn2 & 31) >> 3)) << 3)) = fr;
  }
}

// ---------------- readout tail: logits from precomputed folded weights ----------
__global__ void head(const float* __restrict__ mag, const float* __restrict__ hw,
                     float* __restrict__ out) {
  __shared__ float fw[132];
  const int t = threadIdx.x;
  if (t < 132) fw[t] = hw[t];
  __syncthreads();
  const int n = blockIdx.x * 256 + t;
  float a0 = fw[128], a1 = fw[129], a2 = fw[130], a3 = fw[131];
  for (int m = 0; m < 32; ++m) {
    float v = mag[(size_t)m * NN + n];
    a0 += fw[m] * v; a1 += fw[32 + m] * v; a2 += fw[64 + m] * v; a3 += fw[96 + m] * v;
  }
  f4 r; r.x = a0; r.y = a1; r.z = a2; r.w = a3;
  ((f4*)out)[n] = r;
}

extern "C" void kernel_launch(void* const* d_in, const int* in_sizes, int n_in,
                              void* d_out, int out_size, void* d_ws, size_t ws_size,
                              hipStream_t stream) {
  const float* x      = (const float*)d_in[0];
  const float* adj    = (const float*)d_in[1];
  const float* mc_w0  = (const float*)d_in[2];
  const float* mc_b0  = (const float*)d_in[3];
  const float* mc_w1  = (const float*)d_in[4];
  const float* mc_b1  = (const float*)d_in[5];
  const float* mc_w2  = (const float*)d_in[6];
  const float* mc_b2  = (const float*)d_in[7];
  const float* mc_w3  = (const float*)d_in[8];
  const float* mc_b3  = (const float*)d_in[9];
  const float* proj_w = (const float*)d_in[10];
  const float* proj_b = (const float*)d_in[11];
  const float* pat_w  = (const float*)d_in[12];
  const float* pat_b  = (const float*)d_in[13];
  const float* kur_wc = (const float*)d_in[14];
  const float* kur_bc = (const float*)d_in[15];
  const float* kur_wy = (const float*)d_in[16];
  const float* kur_by = (const float*)d_in[17];
  const float* gn_g   = (const float*)d_in[18];
  const float* gn_b   = (const float*)d_in[19];
  const float* ro_w1  = (const float*)d_in[20];
  const float* ro_b1  = (const float*)d_in[21];
  const float* ro_w2  = (const float*)d_in[22];
  const float* ro_b2  = (const float*)d_in[23];
  const float* out_w  = (const float*)d_in[24];
  const float* out_b  = (const float*)d_in[25];
  float* out = (float*)d_out;
  float* Wf = (float*)d_ws;

  // ---- workspace layout (float-word offsets), ~67.4 MB ----
  f16*   adj16    = (f16*)d_ws;                  // 32 MB
  float* part     = Wf + 8388608;                // 8 MB (csp alias)
  float* csp      = part;
  f16*   fragN    = (f16*)(Wf + 10485760);       // 3.5 MB (im2col, then gst frags)
  f16*   fragA    = (f16*)(Wf + 11403264);       // 0.5 MB
  f16*   fragB    = (f16*)(Wf + 11534336);       // 1 MB
  float* xT       = Wf + 11796480;               // 1 MB
  float* A1       = Wf + 12058624;               // 1 MB
  float* A2       = Wf + 12320768;               // 1 MB (magb alias)
  float* s1cat    = Wf + 12582912;               // 2 MB
  float* B1       = Wf + 13107200;               // 2 MB (wpart/Weff alias, early)
  float* wpart    = B1;
  float* Weff     = Wf + 13238272;
  float* B2       = Wf + 13631488;               // 2 MB
  float* gstf     = Wf + 14155776;               // 7 MB; alias after gst2frag:
  float* cbuf     = gstf;                        //   2 MB
  float* x4       = Wf + 14680064;               // 2 MB
  f16*   x4frag   = (f16*)(Wf + 15204352);       // 1 MB
  float* cy       = Wf + 15990784;               // 2 MB
  f16*   zfrag    = (f16*)(Wf + 16515072);       // 1 MB
  f16*   wcyfrag  = (f16*)(Wf + 16777216);       // 112 KB
  f16*   patfrag  = (f16*)(Wf + 16805888);       // 112 KB
  f16*   wcfrag   = (f16*)(Wf + 16834560);       // 32 KB
  f16*   row1frag = (f16*)(Wf + 16842752);       // 32 KB
  float* deg      = Wf + 16850944;               // 16 KB
  float* beff     = Wf + 16855040;               // 128
  float* cyb      = Wf + 16855168;               // 128
  float* statp    = Wf + 16855296;               // 4 KB
  float* hw       = Wf + 16859392;               // 132 (folded head weights)
  float* magb     = A2;

  dim3 b256(256);

  // 1. adj -> fp16 A-frags + degree
  convert_cs2<<<dim3(128, 8), b256, 0, stream>>>(adj, adj16, csp);
  colsum_fin<<<dim3(16), b256, 0, stream>>>(csp, deg);

  // 2. weight folds
  wfold1<<<dim3(16), b256, 0, stream>>>(proj_w, mc_w0, mc_w1, mc_w2, mc_w3, wpart);
  wfold_asm<<<dim3(32), b256, 0, stream>>>(wpart, proj_w, proj_b,
                                           mc_b0, mc_b1, mc_b2, mc_b3, Weff, beff);
  wfold2<<<dim3(14), b256, 0, stream>>>(kur_wy, Weff, beff, kur_by, kur_bc, wcyfrag, cyb);
  wprep<<<dim3(353), b256, 0, stream>>>(pat_w, kur_wc, ro_w1, ro_w2, ro_b2, out_w, out_b,
                                        patfrag, wcfrag, row1frag, hw);

  // 3. x transpose + frags; im2col; cy = conv(x, Wcy) + cyb
  transpose_x<<<dim3(64), b256, 0, stream>>>(x, deg, xT, gstf, fragA);
  im2col<<<dim3(896), b256, 0, stream>>>(x, fragN);
  wgemm<14, 0><<<dim3(128), b256, 0, stream>>>(wcyfrag, fragN, cyb, cy, nullptr);

  // 4. GST first order (F=64, KZ=8; 2048-block adjmm, 256-block reduce)
  adjmm16<64, 8><<<dim3(2048), b256, 0, stream>>>(adj16, fragA, part);
  reduce_P<<<dim3(256), b256, 0, stream>>>(part, xT, xT, A1, fragA, 4,
                                           fragB, 0, gstf, 1, 1, s1cat, deg, 64, 8);
  adjmm16<64, 8><<<dim3(2048), b256, 0, stream>>>(adj16, fragA, part);
  reduce_P<<<dim3(256), b256, 0, stream>>>(part, A1, A1, A2, fragA, 4,
                                           fragB, 64, gstf, 2, 2, s1cat + (size_t)64 * NN, deg, 64, 8);
  adjmm16<64, 8><<<dim3(2048), b256, 0, stream>>>(adj16, fragA, part);
  reduce_P<<<dim3(256), b256, 0, stream>>>(part, A2, nullptr, A1, fragA, 4,
                                           nullptr, 0, nullptr, -1, -1, nullptr, deg, 64, 8);
  adjmm16<64, 8><<<dim3(2048), b256, 0, stream>>>(adj16, fragA, part);
  reduce_P<<<dim3(256), b256, 0, stream>>>(part, A1, A2, A1, nullptr, 4,
                                           nullptr, 0, gstf, 3, 3, nullptr, deg, 64, 8);

  // 5. GST second order (F=128, KZ=4; 1024-block adjmm, 512-block reduce)
  adjmm16<128, 4><<<dim3(1024), b256, 0, stream>>>(adj16, fragB, part);
  reduce_P<<<dim3(512), b256, 0, stream>>>(part, s1cat, nullptr, B1, fragB, 8,
                                           nullptr, 0, nullptr, -1, -1, nullptr, deg, 128, 4);
  adjmm16<128, 4><<<dim3(1024), b256, 0, stream>>>(adj16, fragB, part);
  reduce_P<<<dim3(512), b256, 0, stream>>>(part, B1, B1, B2, fragB, 8,
                                           nullptr, 0, gstf, 4, -1, nullptr, deg, 128, 4);
  adjmm16<128, 4><<<dim3(1024), b256, 0, stream>>>(adj16, fragB, part);
  reduce_P<<<dim3(512), b256, 0, stream>>>(part, B2, nullptr, B1, fragB, 8,
                                           nullptr, 0, nullptr, -1, -1, nullptr, deg, 128, 4);
  adjmm16<128, 4><<<dim3(1024), b256, 0, stream>>>(adj16, fragB, part);
  reduce_P<<<dim3(512), b256, 0, stream>>>(part, B1, B2, B1, nullptr, 8,
                                           nullptr, 0, gstf, 5, 6, nullptr, deg, 128, 4);

  // 6. gst -> n-frags; x0 GEMM + osc-norm; Z0
  gst2frag<<<dim3(64, 7), b256, 0, stream>>>(gstf, fragN);
  wgemm<14, 1><<<dim3(128), b256, 0, stream>>>(patfrag, fragN, pat_b, x4, x4frag);
  wgemm<4, 2><<<dim3(128), b256, 0, stream>>>(wcfrag, x4frag, nullptr, nullptr, zfrag);

  // 7. Kuramoto dynamics: 3 kernels/iter; last iter skips Z + dead x4 store
  for (int q = 0; q < 8; ++q) {
    adjmm16<128, 4><<<dim3(1024), b256, 0, stream>>>(adj16, zfrag, part);
    reduce_stats<<<dim3(512), b256, 0, stream>>>(part, cy, cbuf, statp);
    kur_fin<<<dim3(256), b256, 0, stream>>>(cbuf, statp, gn_g, gn_b, wcfrag,
                                            x4, x4frag, (q < 7) ? zfrag : nullptr);
  }

  // 8. readout magnitude + head (precomputed folded weights)
  wgemm<4, 3><<<dim3(128), b256, 0, stream>>>(row1frag, x4frag, ro_b1, magb, nullptr);
  head<<<dim3(16), b256, 0, stream>>>(magb, hw, out);
}